// Round 9
// baseline (165.695 us; speedup 1.0000x reference)
//
#include <hip/hip_runtime.h>

typedef unsigned short u16;
typedef unsigned u32;
typedef u16 u16x8 __attribute__((ext_vector_type(8)));
typedef u16 u16x4 __attribute__((ext_vector_type(4)));
typedef u32 u32x4 __attribute__((ext_vector_type(4)));
typedef __bf16 bf8 __attribute__((ext_vector_type(8)));
typedef float f32x4 __attribute__((ext_vector_type(4)));
typedef float f32x16 __attribute__((ext_vector_type(16)));

__device__ __forceinline__ u16 f2b(float f) {
  unsigned u = __float_as_uint(f);
  u += 0x7FFFu + ((u >> 16) & 1u);   // RNE
  return (u16)(u >> 16);
}
__device__ __forceinline__ float b2f(u16 h) {
  return __uint_as_float(((unsigned)h) << 16);
}
__device__ __forceinline__ bf8 asbf8(u16x8 v) {
  return __builtin_bit_cast(bf8, v);
}
__device__ __forceinline__ void gll16(const u16* g, u16* l) {
  __builtin_amdgcn_global_load_lds(
      (const __attribute__((address_space(1))) unsigned*)(g),
      (__attribute__((address_space(3))) unsigned*)(l), 16, 0, 0);
}
__device__ __forceinline__ u32 cvtpk(float lo, float hi) {
  u32 r;
  asm("v_cvt_pk_bf16_f32 %0, %1, %2" : "=v"(r) : "v"(lo), "v"(hi));
  return r;
}
// v_permlane32_swap_b32 a, b:  a.hi32lanes <-> b.lo32lanes
__device__ __forceinline__ void plswap(u32& a, u32& b) {
  asm("v_permlane32_swap_b32 %0, %1" : "+v"(a), "+v"(b));
}
__device__ __forceinline__ float max3f(float a, float b, float c) {
  float r;
  asm("v_max3_f32 %0, %1, %2, %3" : "=v"(r) : "v"(a), "v"(b), "v"(c));
  return r;
}
__device__ __forceinline__ float ex2(float x) {
  return __builtin_amdgcn_exp2f(x);
}
#define MFMA32(A,B,C) __builtin_amdgcn_mfma_f32_32x32x16_bf16(A,B,C,0,0,0)

// ---------------- prep kernels ----------------

__global__ __launch_bounds__(256) void xconv(const float* __restrict__ x,
                                             u16* __restrict__ xb) {
  int i = (blockIdx.x * 256 + threadIdx.x) * 4;
  float4 v = *(const float4*)(x + i);
  u16x4 o;
  o[0] = f2b(v.x); o[1] = f2b(v.y); o[2] = f2b(v.z); o[3] = f2b(v.w);
  *(u16x4*)(xb + i) = o;
}

// in [K][N] f32  ->  out [N][K] bf16   (transpose + convert)
__global__ __launch_bounds__(256) void wtrans(const float* __restrict__ in,
                                              u16* __restrict__ out,
                                              int N, int K) {
  __shared__ float tile[32][33];
  int tx = threadIdx.x & 31, ty = threadIdx.x >> 5;
  int n0 = blockIdx.x * 32, k0 = blockIdx.y * 32;
#pragma unroll
  for (int yy = 0; yy < 32; yy += 8)
    tile[ty + yy][tx] = in[(size_t)(k0 + ty + yy) * N + n0 + tx];
  __syncthreads();
#pragma unroll
  for (int yy = 0; yy < 32; yy += 8)
    out[(size_t)(n0 + ty + yy) * K + k0 + tx] = f2b(tile[tx][ty + yy]);
}

// split-K reduce for qkv + fused RoPE. p0 (=qkv region) updated in place.
__global__ __launch_bounds__(256) void reduce_qkv(u16* __restrict__ p0,
                                                  const u16* __restrict__ p1,
                                                  const float* __restrict__ cs,
                                                  const float* __restrict__ sn) {
  int idx = blockIdx.x * 256 + threadIdx.x;      // 2048*384
  int s = idx / 384, c8 = (idx % 384) * 8;
  size_t base = (size_t)s * 3072 + c8;
  if (c8 < 2560) {                               // q or k head: RoPE pairs
    int hc = c8 & 63;
    if (hc >= 32) return;                        // partner handles
    u16x8 a0 = *(const u16x8*)(p0 + base);
    u16x8 a1 = *(const u16x8*)(p1 + base);
    u16x8 b0 = *(const u16x8*)(p0 + base + 32);
    u16x8 b1 = *(const u16x8*)(p1 + base + 32);
    u16x8 oa, ob;
#pragma unroll
    for (int e = 0; e < 8; ++e) {
      float va = b2f(a0[e]) + b2f(a1[e]);
      float vb = b2f(b0[e]) + b2f(b1[e]);
      float c1 = cs[s * 64 + hc + e],      s1 = sn[s * 64 + hc + e];
      float c2 = cs[s * 64 + hc + 32 + e], s2 = sn[s * 64 + hc + 32 + e];
      oa[e] = f2b(va * c1 - vb * s1);
      ob[e] = f2b(vb * c2 + va * s2);
    }
    *(u16x8*)(p0 + base)      = oa;
    *(u16x8*)(p0 + base + 32) = ob;
  } else {                                       // v: plain sum
    u16x8 a0 = *(const u16x8*)(p0 + base);
    u16x8 a1 = *(const u16x8*)(p1 + base);
    u16x8 o;
#pragma unroll
    for (int e = 0; e < 8; ++e) o[e] = f2b(b2f(a0[e]) + b2f(a1[e]));
    *(u16x8*)(p0 + base) = o;
  }
}

// split-K reduce for out-proj -> f32 d_out
__global__ __launch_bounds__(256) void reduce_out(const u16* __restrict__ p0,
                                                  const u16* __restrict__ p1,
                                                  float* __restrict__ out) {
  int idx = blockIdx.x * 256 + threadIdx.x;      // 2048*256
  size_t base = (size_t)idx * 8;
  u16x8 a0 = *(const u16x8*)(p0 + base);
  u16x8 a1 = *(const u16x8*)(p1 + base);
  float4 lo, hi;
  lo.x = b2f(a0[0]) + b2f(a1[0]); lo.y = b2f(a0[1]) + b2f(a1[1]);
  lo.z = b2f(a0[2]) + b2f(a1[2]); lo.w = b2f(a0[3]) + b2f(a1[3]);
  hi.x = b2f(a0[4]) + b2f(a1[4]); hi.y = b2f(a0[5]) + b2f(a1[5]);
  hi.z = b2f(a0[6]) + b2f(a1[6]); hi.w = b2f(a0[7]) + b2f(a1[7]);
  *(float4*)(out + base)     = lo;
  *(float4*)(out + base + 4) = hi;
}

// K -> fragment-major Kf[kh][b][j][hi][la][8]
__global__ __launch_bounds__(256) void ktrans_f(const u16* __restrict__ qkv,
                                                u16* __restrict__ Kf) {
  int tid = blockIdx.x * 256 + threadIdx.x;   // 2048*64
  int s = tid >> 6, cc = tid & 63;
  int kh = cc >> 3, c = cc & 7;
  int j = c >> 1, hi = c & 1;
  int b = s >> 5, la = s & 31;
  u16x8 v = *(const u16x8*)(qkv + (size_t)s * 3072 + 2048 + cc * 8);
  *(u16x8*)(Kf + ((((size_t)(kh * 64 + b) * 4 + j) * 2 + hi) * 32 + la) * 8) = v;
}

// V -> fragment-major Vf[kh][b][f=m*2+jj][hi][la][8]
__global__ __launch_bounds__(256) void vtrans_f(const u16* __restrict__ qkv,
                                                u16* __restrict__ Vf) {
  int tid = blockIdx.x * 256 + threadIdx.x;   // 2048*64
  int s = tid >> 6, cc = tid & 63;
  int kh = cc >> 3, c = cc & 7;
  int m = c >> 2, laB = (c & 3) * 8;
  int b = s >> 5, s5 = s & 31;
  int jj = s5 >> 4, hi = (s5 >> 3) & 1, e = s5 & 7;
  u16x8 v = *(const u16x8*)(qkv + (size_t)s * 3072 + 2560 + cc * 8);
  u16* dst = Vf + (((size_t)(kh * 64 + b) * 4 + m * 2 + jj) * 64 + hi * 32 + laB) * 8 + e;
#pragma unroll
  for (int i = 0; i < 8; ++i) dst[i * 8] = v[i];
}

// ------- split-K GEMM: Cz[M][N] (bf16) = A[M][kbeg:kbeg+KH] * Bt^T --------

__global__ __launch_bounds__(256) void gemm_sk(const u16* __restrict__ A,
                                               const u16* __restrict__ Bt,
                                               u16* __restrict__ C0,
                                               u16* __restrict__ C1,
                                               int N, int Kfull, int KH) {
  __shared__ __align__(16) u16 As[128 * 32];
  __shared__ __align__(16) u16 Bs[128 * 32];
  const int t = threadIdx.x;
  const int lane = t & 63, wid = t >> 6;
  const int wm = (wid >> 1) * 64, wn = (wid & 1) * 64;
  const int la = lane & 15, lg = lane >> 4;
  const int m0 = blockIdx.y * 128, n0 = blockIdx.x * 128;
  const int kbeg = blockIdx.z * KH;
  u16* C = blockIdx.z ? C1 : C0;

  const int c0 = wid * 2;
  const int srow = c0 * 16 + (lane >> 2);
  const int scol = (lane & 3) * 8;
  const u16* Ap = A + (size_t)(m0 + srow) * Kfull + kbeg + scol;
  const u16* Bp = Bt + (size_t)(n0 + srow) * Kfull + kbeg + scol;
  u16* Ad0 = &As[c0 * 512];
  u16* Ad1 = &As[(c0 + 1) * 512];
  u16* Bd0 = &Bs[c0 * 512];
  u16* Bd1 = &Bs[(c0 + 1) * 512];
  const size_t rstep = (size_t)16 * Kfull;

  f32x4 acc[4][4] = {};

  for (int k0 = 0; k0 < KH; k0 += 32) {
    __syncthreads();
    gll16(Ap + k0, Ad0);
    gll16(Ap + k0 + rstep, Ad1);
    gll16(Bp + k0, Bd0);
    gll16(Bp + k0 + rstep, Bd1);
    __syncthreads();
    bf8 af[4], bfr[4];
#pragma unroll
    for (int i = 0; i < 4; ++i)
      af[i] = asbf8(*(const u16x8*)(&As[(wm + i * 16 + la) * 32 + lg * 8]));
#pragma unroll
    for (int j = 0; j < 4; ++j)
      bfr[j] = asbf8(*(const u16x8*)(&Bs[(wn + j * 16 + la) * 32 + lg * 8]));
    __builtin_amdgcn_s_setprio(1);
#pragma unroll
    for (int i = 0; i < 4; ++i)
#pragma unroll
      for (int j = 0; j < 4; ++j)
        acc[i][j] = __builtin_amdgcn_mfma_f32_16x16x32_bf16(af[i], bfr[j],
                                                            acc[i][j], 0, 0, 0);
    __builtin_amdgcn_s_setprio(0);
  }

#pragma unroll
  for (int i = 0; i < 4; ++i)
#pragma unroll
    for (int j = 0; j < 4; ++j)
#pragma unroll
      for (int r = 0; r < 4; ++r) {
        int row = m0 + wm + i * 16 + lg * 4 + r;
        int col = n0 + wn + j * 16 + la;
        C[(size_t)row * N + col] = f2b(acc[i][j][r]);
      }
}

// ------- flash attention: swapped-QK 32x32, 64 q/wave, kv-split x4 -------
// Each wave: two q-fragments (lo: q0w+la, hi: q0w+32+la) share every K/V
// load -> 2x arithmetic intensity per byte. Softmax in-register per half.

#define LOADKV(K0,K1,K2,K3,V0,V1,V2,V3,b) do {                       \
    const u16* kp_ = kfb + (size_t)(b) * 2048;                       \
    K0 = asbf8(*(const u16x8*)(kp_));                                \
    K1 = asbf8(*(const u16x8*)(kp_ + 512));                          \
    K2 = asbf8(*(const u16x8*)(kp_ + 1024));                         \
    K3 = asbf8(*(const u16x8*)(kp_ + 1536));                         \
    const u16* vp_ = vfb + (size_t)(b) * 2048;                       \
    V0 = asbf8(*(const u16x8*)(vp_));                                \
    V1 = asbf8(*(const u16x8*)(vp_ + 512));                          \
    V2 = asbf8(*(const u16x8*)(vp_ + 1024));                         \
    V3 = asbf8(*(const u16x8*)(vp_ + 1536));                         \
  } while (0)

// QK^T for both halves + causal mask + tree-max
#define QKMAX2(K0,K1,K2,K3,b)                                        \
    f32x16 sL = {}, sH = {};                                         \
    __builtin_amdgcn_s_setprio(1);                                   \
    sL = MFMA32(K0, qfL0, sL); sH = MFMA32(K0, qfH0, sH);            \
    sL = MFMA32(K1, qfL1, sL); sH = MFMA32(K1, qfH1, sH);            \
    sL = MFMA32(K2, qfL2, sL); sH = MFMA32(K2, qfH2, sH);            \
    sL = MFMA32(K3, qfL3, sL); sH = MFMA32(K3, qfH3, sH);            \
    __builtin_amdgcn_s_setprio(0);                                   \
    if ((b) >= nb - 2) {                                             \
      _Pragma("unroll") for (int r = 0; r < 16; ++r) {               \
        int kvr = (b) * 32 + (r & 3) + 8 * (r >> 2) + 4 * hi;        \
        if (kvr > q0w + la) sL[r] = -1e30f;                          \
        if (kvr > q0w + 32 + la) sH[r] = -1e30f;                     \
      }                                                              \
    }                                                                \
    float pmL = fmaxf(                                               \
        max3f(max3f(sL[0], sL[1], sL[2]),  max3f(sL[3], sL[4], sL[5]),\
              max3f(sL[6], sL[7], sL[8])),                           \
        max3f(max3f(sL[9], sL[10], sL[11]),                          \
              max3f(sL[12], sL[13], sL[14]), sL[15]));               \
    float pmH = fmaxf(                                               \
        max3f(max3f(sH[0], sH[1], sH[2]),  max3f(sH[3], sH[4], sH[5]),\
              max3f(sH[6], sH[7], sH[8])),                           \
        max3f(max3f(sH[9], sH[10], sH[11]),                          \
              max3f(sH[12], sH[13], sH[14]), sH[15]));

// exp2, row-sums, pack, PV for both halves
#define EXPPV2(V0,V1,V2,V3) do {                                     \
    _Pragma("unroll") for (int r = 0; r < 16; ++r)                   \
      sL[r] = ex2(sL[r] - mrL);                                      \
    _Pragma("unroll") for (int r = 0; r < 16; ++r)                   \
      sH[r] = ex2(sH[r] - mrH);                                      \
    {                                                                \
      float z0 = sL[0]+sL[1], z1 = sL[2]+sL[3], z2 = sL[4]+sL[5];    \
      float z3 = sL[6]+sL[7], z4 = sL[8]+sL[9], z5 = sL[10]+sL[11];  \
      float z6 = sL[12]+sL[13], z7 = sL[14]+sL[15];                  \
      lrL += ((z0+z1)+(z2+z3)) + ((z4+z5)+(z6+z7));                  \
    }                                                                \
    {                                                                \
      float z0 = sH[0]+sH[1], z1 = sH[2]+sH[3], z2 = sH[4]+sH[5];    \
      float z3 = sH[6]+sH[7], z4 = sH[8]+sH[9], z5 = sH[10]+sH[11];  \
      float z6 = sH[12]+sH[13], z7 = sH[14]+sH[15];                  \
      lrH += ((z0+z1)+(z2+z3)) + ((z4+z5)+(z6+z7));                  \
    }                                                                \
    u32 cL0 = cvtpk(sL[0],sL[1]),   cL1 = cvtpk(sL[2],sL[3]);        \
    u32 cL2 = cvtpk(sL[4],sL[5]),   cL3 = cvtpk(sL[6],sL[7]);        \
    u32 cL4 = cvtpk(sL[8],sL[9]),   cL5 = cvtpk(sL[10],sL[11]);      \
    u32 cL6 = cvtpk(sL[12],sL[13]), cL7 = cvtpk(sL[14],sL[15]);      \
    plswap(cL0,cL2); plswap(cL1,cL3); plswap(cL4,cL6); plswap(cL5,cL7);\
    u32 cH0 = cvtpk(sH[0],sH[1]),   cH1 = cvtpk(sH[2],sH[3]);        \
    u32 cH2 = cvtpk(sH[4],sH[5]),   cH3 = cvtpk(sH[6],sH[7]);        \
    u32 cH4 = cvtpk(sH[8],sH[9]),   cH5 = cvtpk(sH[10],sH[11]);      \
    u32 cH6 = cvtpk(sH[12],sH[13]), cH7 = cvtpk(sH[14],sH[15]);      \
    plswap(cH0,cH2); plswap(cH1,cH3); plswap(cH4,cH6); plswap(cH5,cH7);\
    u32x4 tl0; tl0[0]=cL0; tl0[1]=cL1; tl0[2]=cL2; tl0[3]=cL3;       \
    u32x4 tl1; tl1[0]=cL4; tl1[1]=cL5; tl1[2]=cL6; tl1[3]=cL7;       \
    u32x4 th0; th0[0]=cH0; th0[1]=cH1; th0[2]=cH2; th0[3]=cH3;       \
    u32x4 th1; th1[0]=cH4; th1[1]=cH5; th1[2]=cH6; th1[3]=cH7;       \
    bf8 paL0 = __builtin_bit_cast(bf8, tl0);                         \
    bf8 paL1 = __builtin_bit_cast(bf8, tl1);                         \
    bf8 paH0 = __builtin_bit_cast(bf8, th0);                         \
    bf8 paH1 = __builtin_bit_cast(bf8, th1);                         \
    __builtin_amdgcn_s_setprio(1);                                   \
    ol0 = MFMA32(paL0, V0, ol0); oh0 = MFMA32(paH0, V0, oh0);        \
    ol0 = MFMA32(paL1, V1, ol0); oh0 = MFMA32(paH1, V1, oh0);        \
    ol1 = MFMA32(paL0, V2, ol1); oh1 = MFMA32(paH0, V2, oh1);        \
    ol1 = MFMA32(paL1, V3, ol1); oh1 = MFMA32(paH1, V3, oh1);        \
    __builtin_amdgcn_s_setprio(0);                                   \
  } while (0)

// first step of a chunk: set running max directly, no rescale path
#define STEP1(K0,K1,K2,K3,V0,V1,V2,V3,b) do {                        \
    QKMAX2(K0,K1,K2,K3,b)                                            \
    float omL = __shfl_xor(pmL, 32);                                 \
    mrL = fmaxf(pmL, omL);                                           \
    float omH = __shfl_xor(pmH, 32);                                 \
    mrH = fmaxf(pmH, omH);                                           \
    EXPPV2(V0,V1,V2,V3);                                             \
  } while (0)

// steady step: defer-max (T13, THR=8), per half
#define STEP(K0,K1,K2,K3,V0,V1,V2,V3,b) do {                         \
    QKMAX2(K0,K1,K2,K3,b)                                            \
    if (!__all(pmL - mrL <= 8.0f)) {                                 \
      float omL = __shfl_xor(pmL, 32);                               \
      float mnL = fmaxf(mrL, fmaxf(pmL, omL));                       \
      float scL = ex2(mrL - mnL);                                    \
      mrL = mnL; lrL *= scL;                                         \
      _Pragma("unroll") for (int r = 0; r < 16; ++r) {               \
        float scr = __shfl(scL, (r & 3) + 8 * (r >> 2) + 4 * hi);    \
        ol0[r] *= scr; ol1[r] *= scr;                                \
      }                                                              \
    }                                                                \
    if (!__all(pmH - mrH <= 8.0f)) {                                 \
      float omH = __shfl_xor(pmH, 32);                               \
      float mnH = fmaxf(mrH, fmaxf(pmH, omH));                       \
      float scH = ex2(mrH - mnH);                                    \
      mrH = mnH; lrH *= scH;                                         \
      _Pragma("unroll") for (int r = 0; r < 16; ++r) {               \
        float scr = __shfl(scH, (r & 3) + 8 * (r >> 2) + 4 * hi);    \
        oh0[r] *= scr; oh1[r] *= scr;                                \
      }                                                              \
    }                                                                \
    EXPPV2(V0,V1,V2,V3);                                             \
  } while (0)

__global__ __launch_bounds__(256) void attn_fwd(const u16* __restrict__ qkv,
                                                const u16* __restrict__ Kf,
                                                const u16* __restrict__ Vf,
                                                u16* __restrict__ aout) {
  const int head = blockIdx.x;
  const int qt = 31 - (int)blockIdx.y;   // heavy q-tiles dispatch first
  const int nb = 2 * qt + 2;             // 32-kv blocks total
  const int q0w = qt * 64;
  const int kh = head >> 2;              // GROUPS = 4
  const int t = threadIdx.x;
  const int w = t >> 6;                  // wave id = kv-chunk id
  const int lane = t & 63;
  const int la = lane & 31;
  const int hi = lane >> 5;

  __shared__ float mS[4][64];
  __shared__ float lS[4][64];
  __shared__ __align__(16) u16 oS[4][64][72];

  const int base = nb >> 2, rem = nb & 3;
  const int cnt = base + (w < rem);
  const int start = w * base + min(w, rem);

  // Q B-fragments, prescaled by 0.125*log2(e); two q-halves per wave
  bf8 qfL0, qfL1, qfL2, qfL3, qfH0, qfH1, qfH2, qfH3;
  {
    const float SC = 0.125f * 1.44269504088896340736f;
    const u16* qpL = qkv + (size_t)(q0w + la) * 3072 + head * 64 + hi * 8;
    const u16* qpH = qpL + (size_t)32 * 3072;
#define QLOAD(dst, qp, kk) do {                                      \
      u16x8 v = *(const u16x8*)((qp) + (kk) * 16);                   \
      u16x8 sv;                                                      \
      _Pragma("unroll") for (int e = 0; e < 8; ++e)                  \
        sv[e] = f2b(b2f(v[e]) * SC);                                 \
      dst = asbf8(sv);                                               \
    } while (0)
    QLOAD(qfL0, qpL, 0); QLOAD(qfL1, qpL, 1);
    QLOAD(qfL2, qpL, 2); QLOAD(qfL3, qpL, 3);
    QLOAD(qfH0, qpH, 0); QLOAD(qfH1, qpH, 1);
    QLOAD(qfH2, qpH, 2); QLOAD(qfH3, qpH, 3);
#undef QLOAD
  }

  const u16* kfb = Kf + (size_t)kh * 131072 + (size_t)lane * 8;
  const u16* vfb = Vf + (size_t)kh * 131072 + (size_t)lane * 8;

  f32x16 ol0 = {}, ol1 = {}, oh0 = {}, oh1 = {};
  float mrL = -1e30f, lrL = 0.f, mrH = -1e30f, lrH = 0.f;

  bf8 kA0, kA1, kA2, kA3, vA0, vA1, vA2, vA3;
  bf8 kB0, kB1, kB2, kB3, vB0, vB1, vB2, vB3;

  if (cnt > 0) {
    int b = start;
    const int e = start + cnt;
    LOADKV(kA0, kA1, kA2, kA3, vA0, vA1, vA2, vA3, b);
    if (b + 1 < e) LOADKV(kB0, kB1, kB2, kB3, vB0, vB1, vB2, vB3, b + 1);
    STEP1(kA0, kA1, kA2, kA3, vA0, vA1, vA2, vA3, b);
    ++b;
    while (b < e) {
      if (b + 1 < e) LOADKV(kA0, kA1, kA2, kA3, vA0, vA1, vA2, vA3, b + 1);
      STEP(kB0, kB1, kB2, kB3, vB0, vB1, vB2, vB3, b);
      ++b; if (b >= e) break;
      if (b + 1 < e) LOADKV(kB0, kB1, kB2, kB3, vB0, vB1, vB2, vB3, b + 1);
      STEP(kA0, kA1, kA2, kA3, vA0, vA1, vA2, vA3, b);
      ++b;
    }
  }

  // publish partials (m per q row; l half-combined; O bf16)
  {
    float ltL = lrL + __shfl_xor(lrL, 32);
    float ltH = lrH + __shfl_xor(lrH, 32);
    if (lane < 32) {
      mS[w][lane] = mrL;      lS[w][lane] = ltL;
      mS[w][lane + 32] = mrH; lS[w][lane + 32] = ltH;
    }
#pragma unroll
    for (int r = 0; r < 16; ++r) {
      int crow = (r & 3) + 8 * (r >> 2) + 4 * hi;
      oS[w][crow][la]           = f2b(ol0[r]);
      oS[w][crow][la + 32]      = f2b(ol1[r]);
      oS[w][crow + 32][la]      = f2b(oh0[r]);
      oS[w][crow + 32][la + 32] = f2b(oh1[r]);
    }
  }
  __syncthreads();

  // log-sum-exp merge: 512 items (64 q x 8 d-chunks), 2 per thread
#pragma unroll
  for (int it = 0; it < 2; ++it) {
    const int id = t + it * 256;
    const int q = id >> 3, d0 = (id & 7) * 8;
    float m0_ = mS[0][q], m1_ = mS[1][q], m2_ = mS[2][q], m3_ = mS[3][q];
    float mg = fmaxf(fmaxf(m0_, m1_), fmaxf(m2_, m3_));
    float s0 = ex2(m0_ - mg), s1 = ex2(m1_ - mg);
    float s2 = ex2(m2_ - mg), s3 = ex2(m3_ - mg);
    float lg = s0 * lS[0][q] + s1 * lS[1][q] + s2 * lS[2][q] + s3 * lS[3][q];
    float inv = 1.0f / lg;
    u16x8 p0 = *(const u16x8*)&oS[0][q][d0];
    u16x8 p1 = *(const u16x8*)&oS[1][q][d0];
    u16x8 p2 = *(const u16x8*)&oS[2][q][d0];
    u16x8 p3 = *(const u16x8*)&oS[3][q][d0];
    u16x8 outv;
#pragma unroll
    for (int j = 0; j < 8; ++j) {
      float sum = s0 * b2f(p0[j]) + s1 * b2f(p1[j]) +
                  s2 * b2f(p2[j]) + s3 * b2f(p3[j]);
      outv[j] = f2b(sum * inv);
    }
    *(u16x8*)(aout + (size_t)(q0w + q) * 2048 + head * 64 + d0) = outv;
  }
}

// ---------------- launch ----------------

extern "C" void kernel_launch(void* const* d_in, const int* in_sizes, int n_in,
                              void* d_out, int out_size, void* d_ws, size_t ws_size,
                              hipStream_t stream) {
  (void)in_sizes; (void)n_in; (void)out_size; (void)ws_size;
  const float* x  = (const float*)d_in[0];
  const float* wq = (const float*)d_in[1];
  const float* wk = (const float*)d_in[2];
  const float* wv = (const float*)d_in[3];
  const float* wo = (const float*)d_in[4];
  const float* cs = (const float*)d_in[5];
  const float* sn = (const float*)d_in[6];
  // d_in[7] = causal mask, implemented analytically

  u16* ws    = (u16*)d_ws;
  u16* xb    = ws;                         // [2048][2048] bf16 (later aout)
  u16* wqkvT = ws + 4194304;               // [3072][2048] bf16 (later Kf/Vf)
  u16* qkv   = ws + 10485760;              // [2048][3072] bf16; QKV partial z=0 in place
  u16* woT   = ws + 16777216;              // [2048][2048] bf16
  u16* ext   = ws + 20971520;              // [2048][3072] bf16: QKV partial z=1
  u16* Kf    = wqkvT;                      // [8][64][4][2][32][8] after QKV gemm
  u16* Vf    = wqkvT + 1048576;
  u16* aout  = xb;
  u16* op0   = qkv;                        // out-proj partials (qkv region free)
  u16* op1   = ext;

  xconv<<<4096, 256, 0, stream>>>(x, xb);
  wtrans<<<dim3(64, 64), 256, 0, stream>>>(wq, wqkvT, 2048, 2048);
  wtrans<<<dim3(16, 64), 256, 0, stream>>>(wk, wqkvT + (size_t)2048 * 2048, 512, 2048);
  wtrans<<<dim3(16, 64), 256, 0, stream>>>(wv, wqkvT + (size_t)2560 * 2048, 512, 2048);
  wtrans<<<dim3(64, 64), 256, 0, stream>>>(wo, woT, 2048, 2048);

  // QKV: [2048][3072], split-K x2 (768 blocks)
  gemm_sk<<<dim3(24, 16, 2), 256, 0, stream>>>(xb, wqkvT, qkv, ext, 3072, 2048, 1024);
  reduce_qkv<<<3072, 256, 0, stream>>>(qkv, ext, cs, sn);
  ktrans_f<<<512, 256, 0, stream>>>(qkv, Kf);
  vtrans_f<<<512, 256, 0, stream>>>(qkv, Vf);
  attn_fwd<<<dim3(32, 32), 256, 0, stream>>>(qkv, Kf, Vf, aout);
  // out-proj: [2048][2048], split-K x2 (512 blocks)
  gemm_sk<<<dim3(16, 16, 2), 256, 0, stream>>>(aout, woT, op0, op1, 2048, 2048, 1024);
  reduce_out<<<2048, 256, 0, stream>>>(op0, op1, (float*)d_out);
}

// Round 10
// 153.074 us; speedup vs baseline: 1.0825x; 1.0825x over previous
//
#include <hip/hip_runtime.h>

typedef unsigned short u16;
typedef unsigned u32;
typedef u16 u16x8 __attribute__((ext_vector_type(8)));
typedef u16 u16x4 __attribute__((ext_vector_type(4)));
typedef u32 u32x4 __attribute__((ext_vector_type(4)));
typedef __bf16 bf8 __attribute__((ext_vector_type(8)));
typedef float f32x4 __attribute__((ext_vector_type(4)));
typedef float f32x16 __attribute__((ext_vector_type(16)));

__device__ __forceinline__ u16 f2b(float f) {
  unsigned u = __float_as_uint(f);
  u += 0x7FFFu + ((u >> 16) & 1u);   // RNE
  return (u16)(u >> 16);
}
__device__ __forceinline__ float b2f(u16 h) {
  return __uint_as_float(((unsigned)h) << 16);
}
__device__ __forceinline__ bf8 asbf8(u16x8 v) {
  return __builtin_bit_cast(bf8, v);
}
__device__ __forceinline__ void gll16(const u16* g, u16* l) {
  __builtin_amdgcn_global_load_lds(
      (const __attribute__((address_space(1))) unsigned*)(g),
      (__attribute__((address_space(3))) unsigned*)(l), 16, 0, 0);
}
__device__ __forceinline__ u32 cvtpk(float lo, float hi) {
  u32 r;
  asm("v_cvt_pk_bf16_f32 %0, %1, %2" : "=v"(r) : "v"(lo), "v"(hi));
  return r;
}
// v_permlane32_swap_b32 a, b:  a.hi32lanes <-> b.lo32lanes
__device__ __forceinline__ void plswap(u32& a, u32& b) {
  asm("v_permlane32_swap_b32 %0, %1" : "+v"(a), "+v"(b));
}
__device__ __forceinline__ float ex2(float x) {
  return __builtin_amdgcn_exp2f(x);
}
#define MFMA32(A,B,C) __builtin_amdgcn_mfma_f32_32x32x16_bf16(A,B,C,0,0,0)

// ---------------- prep kernels ----------------

__global__ __launch_bounds__(256) void xconv(const float* __restrict__ x,
                                             u16* __restrict__ xb) {
  int i = (blockIdx.x * 256 + threadIdx.x) * 4;
  float4 v = *(const float4*)(x + i);
  u16x4 o;
  o[0] = f2b(v.x); o[1] = f2b(v.y); o[2] = f2b(v.z); o[3] = f2b(v.w);
  *(u16x4*)(xb + i) = o;
}

// in [K][N] f32  ->  out [N][K] bf16   (transpose + convert)
__global__ __launch_bounds__(256) void wtrans(const float* __restrict__ in,
                                              u16* __restrict__ out,
                                              int N, int K) {
  __shared__ float tile[32][33];
  int tx = threadIdx.x & 31, ty = threadIdx.x >> 5;
  int n0 = blockIdx.x * 32, k0 = blockIdx.y * 32;
#pragma unroll
  for (int yy = 0; yy < 32; yy += 8)
    tile[ty + yy][tx] = in[(size_t)(k0 + ty + yy) * N + n0 + tx];
  __syncthreads();
#pragma unroll
  for (int yy = 0; yy < 32; yy += 8)
    out[(size_t)(n0 + ty + yy) * K + k0 + tx] = f2b(tile[tx][ty + yy]);
}

// split-K reduce for qkv + fused RoPE. p0 (=qkv region) updated in place.
__global__ __launch_bounds__(256) void reduce_qkv(u16* __restrict__ p0,
                                                  const u16* __restrict__ p1,
                                                  const float* __restrict__ cs,
                                                  const float* __restrict__ sn) {
  int idx = blockIdx.x * 256 + threadIdx.x;      // 2048*384
  int s = idx / 384, c8 = (idx % 384) * 8;
  size_t base = (size_t)s * 3072 + c8;
  if (c8 < 2560) {                               // q or k head: RoPE pairs
    int hc = c8 & 63;
    if (hc >= 32) return;                        // partner handles
    u16x8 a0 = *(const u16x8*)(p0 + base);
    u16x8 a1 = *(const u16x8*)(p1 + base);
    u16x8 b0 = *(const u16x8*)(p0 + base + 32);
    u16x8 b1 = *(const u16x8*)(p1 + base + 32);
    u16x8 oa, ob;
#pragma unroll
    for (int e = 0; e < 8; ++e) {
      float va = b2f(a0[e]) + b2f(a1[e]);
      float vb = b2f(b0[e]) + b2f(b1[e]);
      float c1 = cs[s * 64 + hc + e],      s1 = sn[s * 64 + hc + e];
      float c2 = cs[s * 64 + hc + 32 + e], s2 = sn[s * 64 + hc + 32 + e];
      oa[e] = f2b(va * c1 - vb * s1);
      ob[e] = f2b(vb * c2 + va * s2);
    }
    *(u16x8*)(p0 + base)      = oa;
    *(u16x8*)(p0 + base + 32) = ob;
  } else {                                       // v: plain sum
    u16x8 a0 = *(const u16x8*)(p0 + base);
    u16x8 a1 = *(const u16x8*)(p1 + base);
    u16x8 o;
#pragma unroll
    for (int e = 0; e < 8; ++e) o[e] = f2b(b2f(a0[e]) + b2f(a1[e]));
    *(u16x8*)(p0 + base) = o;
  }
}

// split-K reduce for out-proj -> f32 d_out
__global__ __launch_bounds__(256) void reduce_out(const u16* __restrict__ p0,
                                                  const u16* __restrict__ p1,
                                                  float* __restrict__ out) {
  int idx = blockIdx.x * 256 + threadIdx.x;      // 2048*256
  size_t base = (size_t)idx * 8;
  u16x8 a0 = *(const u16x8*)(p0 + base);
  u16x8 a1 = *(const u16x8*)(p1 + base);
  float4 lo, hi;
  lo.x = b2f(a0[0]) + b2f(a1[0]); lo.y = b2f(a0[1]) + b2f(a1[1]);
  lo.z = b2f(a0[2]) + b2f(a1[2]); lo.w = b2f(a0[3]) + b2f(a1[3]);
  hi.x = b2f(a0[4]) + b2f(a1[4]); hi.y = b2f(a0[5]) + b2f(a1[5]);
  hi.z = b2f(a0[6]) + b2f(a1[6]); hi.w = b2f(a0[7]) + b2f(a1[7]);
  *(float4*)(out + base)     = lo;
  *(float4*)(out + base + 4) = hi;
}

// K -> fragment-major Kf[kh][b][j][hi][la][8]
__global__ __launch_bounds__(256) void ktrans_f(const u16* __restrict__ qkv,
                                                u16* __restrict__ Kf) {
  int tid = blockIdx.x * 256 + threadIdx.x;   // 2048*64
  int s = tid >> 6, cc = tid & 63;
  int kh = cc >> 3, c = cc & 7;
  int j = c >> 1, hi = c & 1;
  int b = s >> 5, la = s & 31;
  u16x8 v = *(const u16x8*)(qkv + (size_t)s * 3072 + 2048 + cc * 8);
  *(u16x8*)(Kf + ((((size_t)(kh * 64 + b) * 4 + j) * 2 + hi) * 32 + la) * 8) = v;
}

// V -> fragment-major Vf[kh][b][f=m*2+jj][hi][la][8]
__global__ __launch_bounds__(256) void vtrans_f(const u16* __restrict__ qkv,
                                                u16* __restrict__ Vf) {
  int tid = blockIdx.x * 256 + threadIdx.x;   // 2048*64
  int s = tid >> 6, cc = tid & 63;
  int kh = cc >> 3, c = cc & 7;
  int m = c >> 2, laB = (c & 3) * 8;
  int b = s >> 5, s5 = s & 31;
  int jj = s5 >> 4, hi = (s5 >> 3) & 1, e = s5 & 7;
  u16x8 v = *(const u16x8*)(qkv + (size_t)s * 3072 + 2560 + cc * 8);
  u16* dst = Vf + (((size_t)(kh * 64 + b) * 4 + m * 2 + jj) * 64 + hi * 32 + laB) * 8 + e;
#pragma unroll
  for (int i = 0; i < 8; ++i) dst[i * 8] = v[i];
}

// ------- split-K GEMM: Cz[M][N] (bf16) = A[M][kbeg:kbeg+KH] * Bt^T --------

__global__ __launch_bounds__(256) void gemm_sk(const u16* __restrict__ A,
                                               const u16* __restrict__ Bt,
                                               u16* __restrict__ C0,
                                               u16* __restrict__ C1,
                                               int N, int Kfull, int KH) {
  __shared__ __align__(16) u16 As[128 * 32];
  __shared__ __align__(16) u16 Bs[128 * 32];
  const int t = threadIdx.x;
  const int lane = t & 63, wid = t >> 6;
  const int wm = (wid >> 1) * 64, wn = (wid & 1) * 64;
  const int la = lane & 15, lg = lane >> 4;
  const int m0 = blockIdx.y * 128, n0 = blockIdx.x * 128;
  const int kbeg = blockIdx.z * KH;
  u16* C = blockIdx.z ? C1 : C0;

  const int c0 = wid * 2;
  const int srow = c0 * 16 + (lane >> 2);
  const int scol = (lane & 3) * 8;
  const u16* Ap = A + (size_t)(m0 + srow) * Kfull + kbeg + scol;
  const u16* Bp = Bt + (size_t)(n0 + srow) * Kfull + kbeg + scol;
  u16* Ad0 = &As[c0 * 512];
  u16* Ad1 = &As[(c0 + 1) * 512];
  u16* Bd0 = &Bs[c0 * 512];
  u16* Bd1 = &Bs[(c0 + 1) * 512];
  const size_t rstep = (size_t)16 * Kfull;

  f32x4 acc[4][4] = {};

  for (int k0 = 0; k0 < KH; k0 += 32) {
    __syncthreads();
    gll16(Ap + k0, Ad0);
    gll16(Ap + k0 + rstep, Ad1);
    gll16(Bp + k0, Bd0);
    gll16(Bp + k0 + rstep, Bd1);
    __syncthreads();
    bf8 af[4], bfr[4];
#pragma unroll
    for (int i = 0; i < 4; ++i)
      af[i] = asbf8(*(const u16x8*)(&As[(wm + i * 16 + la) * 32 + lg * 8]));
#pragma unroll
    for (int j = 0; j < 4; ++j)
      bfr[j] = asbf8(*(const u16x8*)(&Bs[(wn + j * 16 + la) * 32 + lg * 8]));
    __builtin_amdgcn_s_setprio(1);
#pragma unroll
    for (int i = 0; i < 4; ++i)
#pragma unroll
      for (int j = 0; j < 4; ++j)
        acc[i][j] = __builtin_amdgcn_mfma_f32_16x16x32_bf16(af[i], bfr[j],
                                                            acc[i][j], 0, 0, 0);
    __builtin_amdgcn_s_setprio(0);
  }

#pragma unroll
  for (int i = 0; i < 4; ++i)
#pragma unroll
    for (int j = 0; j < 4; ++j)
#pragma unroll
      for (int r = 0; r < 4; ++r) {
        int row = m0 + wm + i * 16 + lg * 4 + r;
        int col = n0 + wn + j * 16 + la;
        C[(size_t)row * N + col] = f2b(acc[i][j][r]);
      }
}

// ---- flash attention: swapped-QK 32x32, kv-split x4, STATIC-MAX softmax ---
// P = 2^(s - 32): softmax shift-invariance + bf16's constant relative
// precision make a fixed shift exact enough; removes max-tree/defer/rescale
// and makes all partials share m -> merge is a plain sum.

#define LOADKV(K0,K1,K2,K3,V0,V1,V2,V3,b) do {                       \
    const u16* kp_ = kfb + (size_t)(b) * 2048;                       \
    K0 = asbf8(*(const u16x8*)(kp_));                                \
    K1 = asbf8(*(const u16x8*)(kp_ + 512));                          \
    K2 = asbf8(*(const u16x8*)(kp_ + 1024));                         \
    K3 = asbf8(*(const u16x8*)(kp_ + 1536));                         \
    const u16* vp_ = vfb + (size_t)(b) * 2048;                       \
    V0 = asbf8(*(const u16x8*)(vp_));                                \
    V1 = asbf8(*(const u16x8*)(vp_ + 512));                          \
    V2 = asbf8(*(const u16x8*)(vp_ + 1024));                         \
    V3 = asbf8(*(const u16x8*)(vp_ + 1536));                         \
  } while (0)

#define STEP(K0,K1,K2,K3,V0,V1,V2,V3,b) do {                         \
    f32x16 s = {};                                                   \
    __builtin_amdgcn_s_setprio(1);                                   \
    s = MFMA32(K0, qf0, s);                                          \
    s = MFMA32(K1, qf1, s);                                          \
    s = MFMA32(K2, qf2, s);                                          \
    s = MFMA32(K3, qf3, s);                                          \
    __builtin_amdgcn_s_setprio(0);                                   \
    if ((b) == nb - 1) {                                             \
      _Pragma("unroll") for (int r = 0; r < 16; ++r) {               \
        int kvr = (b) * 32 + (r & 3) + 8 * (r >> 2) + 4 * hi;        \
        if (kvr > q0w + la) s[r] = -1e30f;                           \
      }                                                              \
    }                                                                \
    _Pragma("unroll") for (int r = 0; r < 16; ++r)                   \
      s[r] = ex2(s[r] - 32.0f);                                      \
    float z0 = s[0] + s[1],   z1 = s[2] + s[3];                      \
    float z2 = s[4] + s[5],   z3 = s[6] + s[7];                      \
    float z4 = s[8] + s[9],   z5 = s[10] + s[11];                    \
    float z6 = s[12] + s[13], z7 = s[14] + s[15];                    \
    l_run += ((z0 + z1) + (z2 + z3)) + ((z4 + z5) + (z6 + z7));      \
    u32 c0 = cvtpk(s[0], s[1]),   c1 = cvtpk(s[2], s[3]);            \
    u32 c2 = cvtpk(s[4], s[5]),   c3 = cvtpk(s[6], s[7]);            \
    u32 c4 = cvtpk(s[8], s[9]),   c5 = cvtpk(s[10], s[11]);          \
    u32 c6 = cvtpk(s[12], s[13]), c7 = cvtpk(s[14], s[15]);          \
    plswap(c0, c2); plswap(c1, c3); plswap(c4, c6); plswap(c5, c7);  \
    u32x4 t0; t0[0] = c0; t0[1] = c1; t0[2] = c2; t0[3] = c3;        \
    u32x4 t1; t1[0] = c4; t1[1] = c5; t1[2] = c6; t1[3] = c7;        \
    bf8 pa0 = __builtin_bit_cast(bf8, t0);                           \
    bf8 pa1 = __builtin_bit_cast(bf8, t1);                           \
    __builtin_amdgcn_s_setprio(1);                                   \
    o0 = MFMA32(pa0, V0, o0);                                        \
    o0 = MFMA32(pa1, V1, o0);                                        \
    o1 = MFMA32(pa0, V2, o1);                                        \
    o1 = MFMA32(pa1, V3, o1);                                        \
    __builtin_amdgcn_s_setprio(0);                                   \
  } while (0)

__global__ __launch_bounds__(256) void attn_fwd(const u16* __restrict__ qkv,
                                                const u16* __restrict__ Kf,
                                                const u16* __restrict__ Vf,
                                                u16* __restrict__ aout) {
  const int head = blockIdx.x;
  const int qt = 63 - (int)blockIdx.y;   // heavy q-tiles dispatch first
  const int nb = qt + 1;                 // 32-kv blocks total
  const int q0w = qt * 32;
  const int kh = head >> 2;              // GROUPS = 4
  const int t = threadIdx.x;
  const int w = t >> 6;                  // wave id = kv-chunk id
  const int lane = t & 63;
  const int la = lane & 31;
  const int hi = lane >> 5;

  __shared__ float lS[4][32];
  __shared__ __align__(16) u16 oS[4][32][72];

  const int base = nb >> 2, rem = nb & 3;
  const int cnt = base + (w < rem);
  const int start = w * base + min(w, rem);

  // Q B-fragments, prescaled by 0.125*log2(e) (base-2 softmax domain)
  bf8 qf0, qf1, qf2, qf3;
  {
    const u16* qp = qkv + (size_t)(q0w + la) * 3072 + head * 64 + hi * 8;
    const float SC = 0.125f * 1.44269504088896340736f;
#define QLOAD(dst, kk) do {                                          \
      u16x8 v = *(const u16x8*)(qp + (kk) * 16);                     \
      u16x8 sv;                                                      \
      _Pragma("unroll") for (int e = 0; e < 8; ++e)                  \
        sv[e] = f2b(b2f(v[e]) * SC);                                 \
      dst = asbf8(sv);                                               \
    } while (0)
    QLOAD(qf0, 0); QLOAD(qf1, 1); QLOAD(qf2, 2); QLOAD(qf3, 3);
#undef QLOAD
  }

  const u16* kfb = Kf + (size_t)kh * 131072 + (size_t)lane * 8;
  const u16* vfb = Vf + (size_t)kh * 131072 + (size_t)lane * 8;

  f32x16 o0 = {}, o1 = {};
  float l_run = 0.f;

  bf8 kA0, kA1, kA2, kA3, vA0, vA1, vA2, vA3;
  bf8 kB0, kB1, kB2, kB3, vB0, vB1, vB2, vB3;

  if (cnt > 0) {
    int b = start;
    const int e = start + cnt;
    LOADKV(kA0, kA1, kA2, kA3, vA0, vA1, vA2, vA3, b);
    for (;;) {
      if (b + 1 < e) LOADKV(kB0, kB1, kB2, kB3, vB0, vB1, vB2, vB3, b + 1);
      STEP(kA0, kA1, kA2, kA3, vA0, vA1, vA2, vA3, b);
      ++b; if (b >= e) break;
      if (b + 1 < e) LOADKV(kA0, kA1, kA2, kA3, vA0, vA1, vA2, vA3, b + 1);
      STEP(kB0, kB1, kB2, kB3, vB0, vB1, vB2, vB3, b);
      ++b; if (b >= e) break;
    }
  }

  // publish partials: l (half-combined) and O (bf16); all share m=32
  {
    float lt = l_run + __shfl_xor(l_run, 32);
    if (lane < 32) lS[w][lane] = lt;
#pragma unroll
    for (int r = 0; r < 16; ++r) {
      int crow = (r & 3) + 8 * (r >> 2) + 4 * hi;
      oS[w][crow][la]      = f2b(o0[r]);
      oS[w][crow][la + 32] = f2b(o1[r]);
    }
  }
  __syncthreads();

  // merge: plain sums (shared m). thread t -> q = t>>3, d0 = (t&7)*8
  {
    const int q = t >> 3, d0 = (t & 7) * 8;
    float lg = (lS[0][q] + lS[1][q]) + (lS[2][q] + lS[3][q]);
    float inv = 1.0f / lg;
    u16x8 p0 = *(const u16x8*)&oS[0][q][d0];
    u16x8 p1 = *(const u16x8*)&oS[1][q][d0];
    u16x8 p2 = *(const u16x8*)&oS[2][q][d0];
    u16x8 p3 = *(const u16x8*)&oS[3][q][d0];
    u16x8 outv;
#pragma unroll
    for (int j = 0; j < 8; ++j) {
      float sum = (b2f(p0[j]) + b2f(p1[j])) + (b2f(p2[j]) + b2f(p3[j]));
      outv[j] = f2b(sum * inv);
    }
    *(u16x8*)(aout + (size_t)(q0w + q) * 2048 + head * 64 + d0) = outv;
  }
}

// ---------------- launch ----------------

extern "C" void kernel_launch(void* const* d_in, const int* in_sizes, int n_in,
                              void* d_out, int out_size, void* d_ws, size_t ws_size,
                              hipStream_t stream) {
  (void)in_sizes; (void)n_in; (void)out_size; (void)ws_size;
  const float* x  = (const float*)d_in[0];
  const float* wq = (const float*)d_in[1];
  const float* wk = (const float*)d_in[2];
  const float* wv = (const float*)d_in[3];
  const float* wo = (const float*)d_in[4];
  const float* cs = (const float*)d_in[5];
  const float* sn = (const float*)d_in[6];
  // d_in[7] = causal mask, implemented analytically

  u16* ws    = (u16*)d_ws;
  u16* xb    = ws;                         // [2048][2048] bf16 (later aout)
  u16* wqkvT = ws + 4194304;               // [3072][2048] bf16 (later Kf/Vf)
  u16* qkv   = ws + 10485760;              // [2048][3072] bf16; QKV partial z=0 in place
  u16* woT   = ws + 16777216;              // [2048][2048] bf16
  u16* ext   = ws + 20971520;              // [2048][3072] bf16: QKV partial z=1
  u16* Kf    = wqkvT;                      // [8][64][4][2][32][8] after QKV gemm
  u16* Vf    = wqkvT + 1048576;
  u16* aout  = xb;
  u16* op0   = qkv;                        // out-proj partials (qkv region free)
  u16* op1   = ext;

  xconv<<<4096, 256, 0, stream>>>(x, xb);
  wtrans<<<dim3(64, 64), 256, 0, stream>>>(wq, wqkvT, 2048, 2048);
  wtrans<<<dim3(16, 64), 256, 0, stream>>>(wk, wqkvT + (size_t)2048 * 2048, 512, 2048);
  wtrans<<<dim3(16, 64), 256, 0, stream>>>(wv, wqkvT + (size_t)2560 * 2048, 512, 2048);
  wtrans<<<dim3(64, 64), 256, 0, stream>>>(wo, woT, 2048, 2048);

  // QKV: [2048][3072], split-K x2 (768 blocks)
  gemm_sk<<<dim3(24, 16, 2), 256, 0, stream>>>(xb, wqkvT, qkv, ext, 3072, 2048, 1024);
  reduce_qkv<<<3072, 256, 0, stream>>>(qkv, ext, cs, sn);
  ktrans_f<<<512, 256, 0, stream>>>(qkv, Kf);
  vtrans_f<<<512, 256, 0, stream>>>(qkv, Vf);
  attn_fwd<<<dim3(32, 64), 256, 0, stream>>>(qkv, Kf, Vf, aout);
  // out-proj: [2048][2048], split-K x2 (512 blocks)
  gemm_sk<<<dim3(16, 16, 2), 256, 0, stream>>>(aout, woT, op0, op1, 2048, 2048, 1024);
  reduce_out<<<2048, 256, 0, stream>>>(op0, op1, (float*)d_out);
}

// Round 11
// 151.147 us; speedup vs baseline: 1.0962x; 1.0127x over previous
//
#include <hip/hip_runtime.h>

typedef unsigned short u16;
typedef unsigned u32;
typedef u16 u16x8 __attribute__((ext_vector_type(8)));
typedef u16 u16x4 __attribute__((ext_vector_type(4)));
typedef u32 u32x4 __attribute__((ext_vector_type(4)));
typedef __bf16 bf8 __attribute__((ext_vector_type(8)));
typedef float f32x4 __attribute__((ext_vector_type(4)));
typedef float f32x16 __attribute__((ext_vector_type(16)));

__device__ __forceinline__ u16 f2b(float f) {
  unsigned u = __float_as_uint(f);
  u += 0x7FFFu + ((u >> 16) & 1u);   // RNE
  return (u16)(u >> 16);
}
__device__ __forceinline__ float b2f(u16 h) {
  return __uint_as_float(((unsigned)h) << 16);
}
__device__ __forceinline__ bf8 asbf8(u16x8 v) {
  return __builtin_bit_cast(bf8, v);
}
__device__ __forceinline__ void gll16(const u16* g, u16* l) {
  __builtin_amdgcn_global_load_lds(
      (const __attribute__((address_space(1))) unsigned*)(g),
      (__attribute__((address_space(3))) unsigned*)(l), 16, 0, 0);
}
__device__ __forceinline__ u32 cvtpk(float lo, float hi) {
  u32 r;
  asm("v_cvt_pk_bf16_f32 %0, %1, %2" : "=v"(r) : "v"(lo), "v"(hi));
  return r;
}
// v_permlane32_swap_b32 a, b:  a.hi32lanes <-> b.lo32lanes
__device__ __forceinline__ void plswap(u32& a, u32& b) {
  asm("v_permlane32_swap_b32 %0, %1" : "+v"(a), "+v"(b));
}
__device__ __forceinline__ float ex2(float x) {
  return __builtin_amdgcn_exp2f(x);
}
#define MFMA32(A,B,C) __builtin_amdgcn_mfma_f32_32x32x16_bf16(A,B,C,0,0,0)

// ---------------- prep kernels ----------------

__global__ __launch_bounds__(256) void xconv(const float* __restrict__ x,
                                             u16* __restrict__ xb) {
  int i = (blockIdx.x * 256 + threadIdx.x) * 4;
  float4 v = *(const float4*)(x + i);
  u16x4 o;
  o[0] = f2b(v.x); o[1] = f2b(v.y); o[2] = f2b(v.z); o[3] = f2b(v.w);
  *(u16x4*)(xb + i) = o;
}

// in [K][N] f32  ->  out [N][K] bf16   (transpose + convert)
__global__ __launch_bounds__(256) void wtrans(const float* __restrict__ in,
                                              u16* __restrict__ out,
                                              int N, int K) {
  __shared__ float tile[32][33];
  int tx = threadIdx.x & 31, ty = threadIdx.x >> 5;
  int n0 = blockIdx.x * 32, k0 = blockIdx.y * 32;
#pragma unroll
  for (int yy = 0; yy < 32; yy += 8)
    tile[ty + yy][tx] = in[(size_t)(k0 + ty + yy) * N + n0 + tx];
  __syncthreads();
#pragma unroll
  for (int yy = 0; yy < 32; yy += 8)
    out[(size_t)(n0 + ty + yy) * K + k0 + tx] = f2b(tile[tx][ty + yy]);
}

// split-K reduce for qkv + fused RoPE. p0 (=qkv region) updated in place.
__global__ __launch_bounds__(256) void reduce_qkv(u16* __restrict__ p0,
                                                  const u16* __restrict__ p1,
                                                  const float* __restrict__ cs,
                                                  const float* __restrict__ sn) {
  int idx = blockIdx.x * 256 + threadIdx.x;      // 2048*384
  int s = idx / 384, c8 = (idx % 384) * 8;
  size_t base = (size_t)s * 3072 + c8;
  if (c8 < 2560) {                               // q or k head: RoPE pairs
    int hc = c8 & 63;
    if (hc >= 32) return;                        // partner handles
    u16x8 a0 = *(const u16x8*)(p0 + base);
    u16x8 a1 = *(const u16x8*)(p1 + base);
    u16x8 b0 = *(const u16x8*)(p0 + base + 32);
    u16x8 b1 = *(const u16x8*)(p1 + base + 32);
    u16x8 oa, ob;
#pragma unroll
    for (int e = 0; e < 8; ++e) {
      float va = b2f(a0[e]) + b2f(a1[e]);
      float vb = b2f(b0[e]) + b2f(b1[e]);
      float c1 = cs[s * 64 + hc + e],      s1 = sn[s * 64 + hc + e];
      float c2 = cs[s * 64 + hc + 32 + e], s2 = sn[s * 64 + hc + 32 + e];
      oa[e] = f2b(va * c1 - vb * s1);
      ob[e] = f2b(vb * c2 + va * s2);
    }
    *(u16x8*)(p0 + base)      = oa;
    *(u16x8*)(p0 + base + 32) = ob;
  } else {                                       // v: plain sum
    u16x8 a0 = *(const u16x8*)(p0 + base);
    u16x8 a1 = *(const u16x8*)(p1 + base);
    u16x8 o;
#pragma unroll
    for (int e = 0; e < 8; ++e) o[e] = f2b(b2f(a0[e]) + b2f(a1[e]));
    *(u16x8*)(p0 + base) = o;
  }
}

// split-K reduce for out-proj -> f32 d_out
__global__ __launch_bounds__(256) void reduce_out(const u16* __restrict__ p0,
                                                  const u16* __restrict__ p1,
                                                  float* __restrict__ out) {
  int idx = blockIdx.x * 256 + threadIdx.x;      // 2048*256
  size_t base = (size_t)idx * 8;
  u16x8 a0 = *(const u16x8*)(p0 + base);
  u16x8 a1 = *(const u16x8*)(p1 + base);
  float4 lo, hi;
  lo.x = b2f(a0[0]) + b2f(a1[0]); lo.y = b2f(a0[1]) + b2f(a1[1]);
  lo.z = b2f(a0[2]) + b2f(a1[2]); lo.w = b2f(a0[3]) + b2f(a1[3]);
  hi.x = b2f(a0[4]) + b2f(a1[4]); hi.y = b2f(a0[5]) + b2f(a1[5]);
  hi.z = b2f(a0[6]) + b2f(a1[6]); hi.w = b2f(a0[7]) + b2f(a1[7]);
  *(float4*)(out + base)     = lo;
  *(float4*)(out + base + 4) = hi;
}

// K -> fragment-major Kf[kh][b][j][hi][la][8]
__global__ __launch_bounds__(256) void ktrans_f(const u16* __restrict__ qkv,
                                                u16* __restrict__ Kf) {
  int tid = blockIdx.x * 256 + threadIdx.x;   // 2048*64
  int s = tid >> 6, cc = tid & 63;
  int kh = cc >> 3, c = cc & 7;
  int j = c >> 1, hi = c & 1;
  int b = s >> 5, la = s & 31;
  u16x8 v = *(const u16x8*)(qkv + (size_t)s * 3072 + 2048 + cc * 8);
  *(u16x8*)(Kf + ((((size_t)(kh * 64 + b) * 4 + j) * 2 + hi) * 32 + la) * 8) = v;
}

// V -> fragment-major Vf[kh][b][f=m*2+jj][hi][la][8]
__global__ __launch_bounds__(256) void vtrans_f(const u16* __restrict__ qkv,
                                                u16* __restrict__ Vf) {
  int tid = blockIdx.x * 256 + threadIdx.x;   // 2048*64
  int s = tid >> 6, cc = tid & 63;
  int kh = cc >> 3, c = cc & 7;
  int m = c >> 2, laB = (c & 3) * 8;
  int b = s >> 5, s5 = s & 31;
  int jj = s5 >> 4, hi = (s5 >> 3) & 1, e = s5 & 7;
  u16x8 v = *(const u16x8*)(qkv + (size_t)s * 3072 + 2560 + cc * 8);
  u16* dst = Vf + (((size_t)(kh * 64 + b) * 4 + m * 2 + jj) * 64 + hi * 32 + laB) * 8 + e;
#pragma unroll
  for (int i = 0; i < 8; ++i) dst[i * 8] = v[i];
}

// ------- split-K GEMM: Cz[M][N] (bf16) = A[M][kbeg:kbeg+KH] * Bt^T --------

__global__ __launch_bounds__(256) void gemm_sk(const u16* __restrict__ A,
                                               const u16* __restrict__ Bt,
                                               u16* __restrict__ C0,
                                               u16* __restrict__ C1,
                                               int N, int Kfull, int KH) {
  __shared__ __align__(16) u16 As[128 * 32];
  __shared__ __align__(16) u16 Bs[128 * 32];
  const int t = threadIdx.x;
  const int lane = t & 63, wid = t >> 6;
  const int wm = (wid >> 1) * 64, wn = (wid & 1) * 64;
  const int la = lane & 15, lg = lane >> 4;
  const int m0 = blockIdx.y * 128, n0 = blockIdx.x * 128;
  const int kbeg = blockIdx.z * KH;
  u16* C = blockIdx.z ? C1 : C0;

  const int c0 = wid * 2;
  const int srow = c0 * 16 + (lane >> 2);
  const int scol = (lane & 3) * 8;
  const u16* Ap = A + (size_t)(m0 + srow) * Kfull + kbeg + scol;
  const u16* Bp = Bt + (size_t)(n0 + srow) * Kfull + kbeg + scol;
  u16* Ad0 = &As[c0 * 512];
  u16* Ad1 = &As[(c0 + 1) * 512];
  u16* Bd0 = &Bs[c0 * 512];
  u16* Bd1 = &Bs[(c0 + 1) * 512];
  const size_t rstep = (size_t)16 * Kfull;

  f32x4 acc[4][4] = {};

  for (int k0 = 0; k0 < KH; k0 += 32) {
    __syncthreads();
    gll16(Ap + k0, Ad0);
    gll16(Ap + k0 + rstep, Ad1);
    gll16(Bp + k0, Bd0);
    gll16(Bp + k0 + rstep, Bd1);
    __syncthreads();
    bf8 af[4], bfr[4];
#pragma unroll
    for (int i = 0; i < 4; ++i)
      af[i] = asbf8(*(const u16x8*)(&As[(wm + i * 16 + la) * 32 + lg * 8]));
#pragma unroll
    for (int j = 0; j < 4; ++j)
      bfr[j] = asbf8(*(const u16x8*)(&Bs[(wn + j * 16 + la) * 32 + lg * 8]));
    __builtin_amdgcn_s_setprio(1);
#pragma unroll
    for (int i = 0; i < 4; ++i)
#pragma unroll
      for (int j = 0; j < 4; ++j)
        acc[i][j] = __builtin_amdgcn_mfma_f32_16x16x32_bf16(af[i], bfr[j],
                                                            acc[i][j], 0, 0, 0);
    __builtin_amdgcn_s_setprio(0);
  }

#pragma unroll
  for (int i = 0; i < 4; ++i)
#pragma unroll
    for (int j = 0; j < 4; ++j)
#pragma unroll
      for (int r = 0; r < 4; ++r) {
        int row = m0 + wm + i * 16 + lg * 4 + r;
        int col = n0 + wn + j * 16 + la;
        C[(size_t)row * N + col] = f2b(acc[i][j][r]);
      }
}

// --- flash attention: LDS-shared KV, 8 waves = 4 q-tiles x 2 kv-halves ----
// Block = (head, 128 q rows). Per step each half stages ONE fragment-major
// kv-block (8KB) into double-buffered LDS; 4 q-waves consume it -> KV
// global/L2 traffic /4. Static-max softmax (shared m=32) => the 2-way
// kv-split merge is a plain sum in LDS (overlaid on staging buffers).

#define STEPL(buf, bb) do {                                          \
    const u16* p_ = &smem[(((h2) << 1) | (buf)) * 4096 + lane8];     \
    bf8 K0 = asbf8(*(const u16x8*)(p_));                             \
    bf8 K1 = asbf8(*(const u16x8*)(p_ + 512));                       \
    bf8 K2 = asbf8(*(const u16x8*)(p_ + 1024));                      \
    bf8 K3 = asbf8(*(const u16x8*)(p_ + 1536));                      \
    bf8 V0 = asbf8(*(const u16x8*)(p_ + 2048));                      \
    bf8 V1 = asbf8(*(const u16x8*)(p_ + 2560));                      \
    bf8 V2 = asbf8(*(const u16x8*)(p_ + 3072));                      \
    bf8 V3 = asbf8(*(const u16x8*)(p_ + 3584));                      \
    f32x16 s = {};                                                   \
    __builtin_amdgcn_s_setprio(1);                                   \
    s = MFMA32(K0, qf0, s);                                          \
    s = MFMA32(K1, qf1, s);                                          \
    s = MFMA32(K2, qf2, s);                                          \
    s = MFMA32(K3, qf3, s);                                          \
    __builtin_amdgcn_s_setprio(0);                                   \
    if ((bb) == kmax) {                                              \
      _Pragma("unroll") for (int r = 0; r < 16; ++r) {               \
        int kvr = (bb) * 32 + (r & 3) + 8 * (r >> 2) + 4 * hi;       \
        if (kvr > q0w + la) s[r] = -1e30f;                           \
      }                                                              \
    }                                                                \
    _Pragma("unroll") for (int r = 0; r < 16; ++r)                   \
      s[r] = ex2(s[r] - 32.0f);                                      \
    float z0 = s[0] + s[1],   z1 = s[2] + s[3];                      \
    float z2 = s[4] + s[5],   z3 = s[6] + s[7];                      \
    float z4 = s[8] + s[9],   z5 = s[10] + s[11];                    \
    float z6 = s[12] + s[13], z7 = s[14] + s[15];                    \
    l_run += ((z0 + z1) + (z2 + z3)) + ((z4 + z5) + (z6 + z7));      \
    u32 c0 = cvtpk(s[0], s[1]),   c1 = cvtpk(s[2], s[3]);            \
    u32 c2 = cvtpk(s[4], s[5]),   c3 = cvtpk(s[6], s[7]);            \
    u32 c4 = cvtpk(s[8], s[9]),   c5 = cvtpk(s[10], s[11]);          \
    u32 c6 = cvtpk(s[12], s[13]), c7 = cvtpk(s[14], s[15]);          \
    plswap(c0, c2); plswap(c1, c3); plswap(c4, c6); plswap(c5, c7);  \
    u32x4 t0; t0[0] = c0; t0[1] = c1; t0[2] = c2; t0[3] = c3;        \
    u32x4 t1; t1[0] = c4; t1[1] = c5; t1[2] = c6; t1[3] = c7;        \
    bf8 pa0 = __builtin_bit_cast(bf8, t0);                           \
    bf8 pa1 = __builtin_bit_cast(bf8, t1);                           \
    __builtin_amdgcn_s_setprio(1);                                   \
    o0 = MFMA32(pa0, V0, o0);                                        \
    o0 = MFMA32(pa1, V1, o0);                                        \
    o1 = MFMA32(pa0, V2, o1);                                        \
    o1 = MFMA32(pa1, V3, o1);                                        \
    __builtin_amdgcn_s_setprio(0);                                   \
  } while (0)

#define STG(bb, buf) do {                                            \
    u16* d_ = &smem[((((h2) << 1) | (buf)) * 4096) + sub * 512];     \
    gll16(Kg + (size_t)(bb) * 2048 + sub * 512 + lane8, d_);         \
    gll16(Vg + (size_t)(bb) * 2048 + sub * 512 + lane8, d_ + 2048);  \
  } while (0)

__global__ __launch_bounds__(512, 4) void attn_fwd(const u16* __restrict__ qkv,
                                                   const u16* __restrict__ Kf,
                                                   const u16* __restrict__ Vf,
                                                   u16* __restrict__ aout) {
  const int head = blockIdx.x;
  const int qb = 15 - (int)blockIdx.y;   // heavy q-blocks dispatch first
  const int Q0 = qb * 128;
  const int Kb = qb * 4;                 // kv-block index of Q0
  const int nb = Kb + 4;                 // kv blocks total (even)
  const int ha = nb >> 1;                // steps; half A: [0,ha), B: [ha,nb)
  const int kh = head >> 2;              // GROUPS = 4
  const int t = threadIdx.x;
  const int w = t >> 6, lane = t & 63;
  const int h2 = w >> 2;                 // kv half
  const int wq = w & 3;                  // q sub-tile
  const int sub = wq;                    // staging chunk
  const int la = lane & 31;
  const int hi = lane >> 5;
  const int lane8 = lane * 8;
  const int q0w = Q0 + 32 * wq;
  const int kmax = Kb + wq;              // this wave's diagonal kv-block

  // staging: smem[0..16383] = 4 slots (half,buf) x 4096 u16 (K 2048 | V 2048)
  // merge overlay: oM[8][32][72] u16 = smem[0..18431]
  __shared__ __align__(16) u16 smem[18432];
  __shared__ float lM[8][32];

  // Q B-fragments, prescaled by 0.125*log2(e) (base-2 softmax domain)
  bf8 qf0, qf1, qf2, qf3;
  {
    const u16* qp = qkv + (size_t)(q0w + la) * 3072 + head * 64 + hi * 8;
    const float SC = 0.125f * 1.44269504088896340736f;
#define QLOAD(dst, kk) do {                                          \
      u16x8 v = *(const u16x8*)(qp + (kk) * 16);                     \
      u16x8 sv;                                                      \
      _Pragma("unroll") for (int e = 0; e < 8; ++e)                  \
        sv[e] = f2b(b2f(v[e]) * SC);                                 \
      dst = asbf8(sv);                                               \
    } while (0)
    QLOAD(qf0, 0); QLOAD(qf1, 1); QLOAD(qf2, 2); QLOAD(qf3, 3);
#undef QLOAD
  }

  const u16* Kg = Kf + (size_t)kh * 131072;
  const u16* Vg = Vf + (size_t)kh * 131072;

  f32x16 o0 = {}, o1 = {};
  float l_run = 0.f;

  // prologue: stage first block of this half into buf 0
  STG(h2 ? ha : 0, 0);
  __syncthreads();

  for (int i = 0; i < ha; ++i) {
    if (i + 1 < ha) STG(h2 ? (ha + i + 1) : (i + 1), (i + 1) & 1);
    const int bb = h2 ? (ha + i) : i;
    if (bb <= kmax) STEPL(i & 1, bb);
    __syncthreads();   // drains next stage (vmcnt 0) + read/write fences
  }

  // publish partials: l (half-combined) and O (bf16) into overlay
  {
    float lt = l_run + __shfl_xor(l_run, 32);
    if (lane < 32) lM[w][lane] = lt;
#pragma unroll
    for (int r = 0; r < 16; ++r) {
      int crow = (r & 3) + 8 * (r >> 2) + 4 * hi;
      smem[(w * 32 + crow) * 72 + la]      = f2b(o0[r]);
      smem[(w * 32 + crow) * 72 + la + 32] = f2b(o1[r]);
    }
  }
  __syncthreads();

  // merge: plain sums (shared m=32). 1024 items (128 q x 8 d-chunks)
#pragma unroll
  for (int it = 0; it < 2; ++it) {
    const int id = t + it * 512;
    const int q = id >> 3, d0 = (id & 7) * 8;
    const int wA = q >> 5, crow = q & 31;
    float inv = 1.0f / (lM[wA][crow] + lM[wA + 4][crow]);
    u16x8 a = *(const u16x8*)&smem[((wA)     * 32 + crow) * 72 + d0];
    u16x8 b = *(const u16x8*)&smem[((wA + 4) * 32 + crow) * 72 + d0];
    u16x8 outv;
#pragma unroll
    for (int j = 0; j < 8; ++j)
      outv[j] = f2b((b2f(a[j]) + b2f(b[j])) * inv);
    *(u16x8*)(aout + (size_t)(Q0 + q) * 2048 + head * 64 + d0) = outv;
  }
}

// ---------------- launch ----------------

extern "C" void kernel_launch(void* const* d_in, const int* in_sizes, int n_in,
                              void* d_out, int out_size, void* d_ws, size_t ws_size,
                              hipStream_t stream) {
  (void)in_sizes; (void)n_in; (void)out_size; (void)ws_size;
  const float* x  = (const float*)d_in[0];
  const float* wq = (const float*)d_in[1];
  const float* wk = (const float*)d_in[2];
  const float* wv = (const float*)d_in[3];
  const float* wo = (const float*)d_in[4];
  const float* cs = (const float*)d_in[5];
  const float* sn = (const float*)d_in[6];
  // d_in[7] = causal mask, implemented analytically

  u16* ws    = (u16*)d_ws;
  u16* xb    = ws;                         // [2048][2048] bf16 (later aout)
  u16* wqkvT = ws + 4194304;               // [3072][2048] bf16 (later Kf/Vf)
  u16* qkv   = ws + 10485760;              // [2048][3072] bf16; QKV partial z=0 in place
  u16* woT   = ws + 16777216;              // [2048][2048] bf16
  u16* ext   = ws + 20971520;              // [2048][3072] bf16: QKV partial z=1
  u16* Kf    = wqkvT;                      // [8][64][4][2][32][8] after QKV gemm
  u16* Vf    = wqkvT + 1048576;
  u16* aout  = xb;
  u16* op0   = qkv;                        // out-proj partials (qkv region free)
  u16* op1   = ext;

  xconv<<<4096, 256, 0, stream>>>(x, xb);
  wtrans<<<dim3(64, 64), 256, 0, stream>>>(wq, wqkvT, 2048, 2048);
  wtrans<<<dim3(16, 64), 256, 0, stream>>>(wk, wqkvT + (size_t)2048 * 2048, 512, 2048);
  wtrans<<<dim3(16, 64), 256, 0, stream>>>(wv, wqkvT + (size_t)2560 * 2048, 512, 2048);
  wtrans<<<dim3(64, 64), 256, 0, stream>>>(wo, woT, 2048, 2048);

  // QKV: [2048][3072], split-K x2 (768 blocks)
  gemm_sk<<<dim3(24, 16, 2), 256, 0, stream>>>(xb, wqkvT, qkv, ext, 3072, 2048, 1024);
  reduce_qkv<<<3072, 256, 0, stream>>>(qkv, ext, cs, sn);
  ktrans_f<<<512, 256, 0, stream>>>(qkv, Kf);
  vtrans_f<<<512, 256, 0, stream>>>(qkv, Vf);
  attn_fwd<<<dim3(32, 16), 512, 0, stream>>>(qkv, Kf, Vf, aout);
  // out-proj: [2048][2048], split-K x2 (512 blocks)
  gemm_sk<<<dim3(16, 16, 2), 256, 0, stream>>>(aout, woT, op0, op1, 2048, 2048, 1024);
  reduce_out<<<2048, 256, 0, stream>>>(op0, op1, (float*)d_out);
}

// Round 12
// 142.555 us; speedup vs baseline: 1.1623x; 1.0603x over previous
//
#include <hip/hip_runtime.h>

typedef unsigned short u16;
typedef unsigned u32;
typedef u16 u16x8 __attribute__((ext_vector_type(8)));
typedef u16 u16x4 __attribute__((ext_vector_type(4)));
typedef u32 u32x4 __attribute__((ext_vector_type(4)));
typedef __bf16 bf8 __attribute__((ext_vector_type(8)));
typedef float f32x4 __attribute__((ext_vector_type(4)));
typedef float f32x16 __attribute__((ext_vector_type(16)));

__device__ __forceinline__ u16 f2b(float f) {
  unsigned u = __float_as_uint(f);
  u += 0x7FFFu + ((u >> 16) & 1u);   // RNE
  return (u16)(u >> 16);
}
__device__ __forceinline__ float b2f(u16 h) {
  return __uint_as_float(((unsigned)h) << 16);
}
__device__ __forceinline__ bf8 asbf8(u16x8 v) {
  return __builtin_bit_cast(bf8, v);
}
__device__ __forceinline__ void gll16(const u16* g, u16* l) {
  __builtin_amdgcn_global_load_lds(
      (const __attribute__((address_space(1))) unsigned*)(g),
      (__attribute__((address_space(3))) unsigned*)(l), 16, 0, 0);
}
__device__ __forceinline__ u32 cvtpk(float lo, float hi) {
  u32 r;
  asm("v_cvt_pk_bf16_f32 %0, %1, %2" : "=v"(r) : "v"(lo), "v"(hi));
  return r;
}
// v_permlane32_swap_b32 a, b:  a.hi32lanes <-> b.lo32lanes
__device__ __forceinline__ void plswap(u32& a, u32& b) {
  asm("v_permlane32_swap_b32 %0, %1" : "+v"(a), "+v"(b));
}
__device__ __forceinline__ float ex2(float x) {
  return __builtin_amdgcn_exp2f(x);
}
#define MFMA32(A,B,C) __builtin_amdgcn_mfma_f32_32x32x16_bf16(A,B,C,0,0,0)

// ---------------- prep kernels ----------------

__global__ __launch_bounds__(256) void xconv(const float* __restrict__ x,
                                             u16* __restrict__ xb) {
  int i = (blockIdx.x * 256 + threadIdx.x) * 4;
  float4 v = *(const float4*)(x + i);
  u16x4 o;
  o[0] = f2b(v.x); o[1] = f2b(v.y); o[2] = f2b(v.z); o[3] = f2b(v.w);
  *(u16x4*)(xb + i) = o;
}

// in [K][N] f32  ->  out [N][K] bf16   (transpose + convert)
__global__ __launch_bounds__(256) void wtrans(const float* __restrict__ in,
                                              u16* __restrict__ out,
                                              int N, int K) {
  __shared__ float tile[32][33];
  int tx = threadIdx.x & 31, ty = threadIdx.x >> 5;
  int n0 = blockIdx.x * 32, k0 = blockIdx.y * 32;
#pragma unroll
  for (int yy = 0; yy < 32; yy += 8)
    tile[ty + yy][tx] = in[(size_t)(k0 + ty + yy) * N + n0 + tx];
  __syncthreads();
#pragma unroll
  for (int yy = 0; yy < 32; yy += 8)
    out[(size_t)(n0 + ty + yy) * K + k0 + tx] = f2b(tile[tx][ty + yy]);
}

// split-K reduce for qkv + fused RoPE. p0 (=qkv region) updated in place.
__global__ __launch_bounds__(256) void reduce_qkv(u16* __restrict__ p0,
                                                  const u16* __restrict__ p1,
                                                  const float* __restrict__ cs,
                                                  const float* __restrict__ sn) {
  int idx = blockIdx.x * 256 + threadIdx.x;      // 2048*384
  int s = idx / 384, c8 = (idx % 384) * 8;
  size_t base = (size_t)s * 3072 + c8;
  if (c8 < 2560) {                               // q or k head: RoPE pairs
    int hc = c8 & 63;
    if (hc >= 32) return;                        // partner handles
    u16x8 a0 = *(const u16x8*)(p0 + base);
    u16x8 a1 = *(const u16x8*)(p1 + base);
    u16x8 b0 = *(const u16x8*)(p0 + base + 32);
    u16x8 b1 = *(const u16x8*)(p1 + base + 32);
    u16x8 oa, ob;
#pragma unroll
    for (int e = 0; e < 8; ++e) {
      float va = b2f(a0[e]) + b2f(a1[e]);
      float vb = b2f(b0[e]) + b2f(b1[e]);
      float c1 = cs[s * 64 + hc + e],      s1 = sn[s * 64 + hc + e];
      float c2 = cs[s * 64 + hc + 32 + e], s2 = sn[s * 64 + hc + 32 + e];
      oa[e] = f2b(va * c1 - vb * s1);
      ob[e] = f2b(vb * c2 + va * s2);
    }
    *(u16x8*)(p0 + base)      = oa;
    *(u16x8*)(p0 + base + 32) = ob;
  } else {                                       // v: plain sum
    u16x8 a0 = *(const u16x8*)(p0 + base);
    u16x8 a1 = *(const u16x8*)(p1 + base);
    u16x8 o;
#pragma unroll
    for (int e = 0; e < 8; ++e) o[e] = f2b(b2f(a0[e]) + b2f(a1[e]));
    *(u16x8*)(p0 + base) = o;
  }
}

// split-K reduce for out-proj -> f32 d_out
__global__ __launch_bounds__(256) void reduce_out(const u16* __restrict__ p0,
                                                  const u16* __restrict__ p1,
                                                  float* __restrict__ out) {
  int idx = blockIdx.x * 256 + threadIdx.x;      // 2048*256
  size_t base = (size_t)idx * 8;
  u16x8 a0 = *(const u16x8*)(p0 + base);
  u16x8 a1 = *(const u16x8*)(p1 + base);
  float4 lo, hi;
  lo.x = b2f(a0[0]) + b2f(a1[0]); lo.y = b2f(a0[1]) + b2f(a1[1]);
  lo.z = b2f(a0[2]) + b2f(a1[2]); lo.w = b2f(a0[3]) + b2f(a1[3]);
  hi.x = b2f(a0[4]) + b2f(a1[4]); hi.y = b2f(a0[5]) + b2f(a1[5]);
  hi.z = b2f(a0[6]) + b2f(a1[6]); hi.w = b2f(a0[7]) + b2f(a1[7]);
  *(float4*)(out + base)     = lo;
  *(float4*)(out + base + 4) = hi;
}

// K -> fragment-major Kf[kh][b][j][hi][la][8]
__global__ __launch_bounds__(256) void ktrans_f(const u16* __restrict__ qkv,
                                                u16* __restrict__ Kf) {
  int tid = blockIdx.x * 256 + threadIdx.x;   // 2048*64
  int s = tid >> 6, cc = tid & 63;
  int kh = cc >> 3, c = cc & 7;
  int j = c >> 1, hi = c & 1;
  int b = s >> 5, la = s & 31;
  u16x8 v = *(const u16x8*)(qkv + (size_t)s * 3072 + 2048 + cc * 8);
  *(u16x8*)(Kf + ((((size_t)(kh * 64 + b) * 4 + j) * 2 + hi) * 32 + la) * 8) = v;
}

// V -> fragment-major Vf[kh][b][f=m*2+jj][hi][la][8]
__global__ __launch_bounds__(256) void vtrans_f(const u16* __restrict__ qkv,
                                                u16* __restrict__ Vf) {
  int tid = blockIdx.x * 256 + threadIdx.x;   // 2048*64
  int s = tid >> 6, cc = tid & 63;
  int kh = cc >> 3, c = cc & 7;
  int m = c >> 2, laB = (c & 3) * 8;
  int b = s >> 5, s5 = s & 31;
  int jj = s5 >> 4, hi = (s5 >> 3) & 1, e = s5 & 7;
  u16x8 v = *(const u16x8*)(qkv + (size_t)s * 3072 + 2560 + cc * 8);
  u16* dst = Vf + (((size_t)(kh * 64 + b) * 4 + m * 2 + jj) * 64 + hi * 32 + laB) * 8 + e;
#pragma unroll
  for (int i = 0; i < 8; ++i) dst[i * 8] = v[i];
}

// ------- split-K GEMM, BK=64, XOR-swizzled LDS ----------------------------
// [128][64] tiles; LDS slot (row, col8) holds global col8^(row&7): linear
// gll16 dest + pre-swizzled per-lane global source (permutes within 128B
// segments -> same cache lines), ds_read applies the same XOR -> 2-way banks.

__global__ __launch_bounds__(256) void gemm_sk(const u16* __restrict__ A,
                                               const u16* __restrict__ Bt,
                                               u16* __restrict__ C0,
                                               u16* __restrict__ C1,
                                               int N, int Kfull, int KH) {
  __shared__ __align__(16) u16 As[128 * 64];
  __shared__ __align__(16) u16 Bs[128 * 64];
  const int t = threadIdx.x;
  const int lane = t & 63, wid = t >> 6;
  const int wm = (wid >> 1) * 64, wn = (wid & 1) * 64;
  const int la = lane & 15, lg = lane >> 4;
  const int m0 = blockIdx.y * 128, n0 = blockIdx.x * 128;
  const int kbeg = blockIdx.z * KH;
  u16* C = blockIdx.z ? C1 : C0;

  // staging: wave wid stages chunks 4w..4w+3 (8 rows x 64 cols each)
  const int srow0 = wid * 32 + (lane >> 3);
  const int scolsw = (((lane & 7) ^ (lane >> 3))) * 8;   // pre-swizzled col
  const u16* Ap = A + (size_t)(m0 + srow0) * Kfull + kbeg + scolsw;
  const u16* Bp = Bt + (size_t)(n0 + srow0) * Kfull + kbeg + scolsw;
  u16* Adst = &As[wid * 2048];
  u16* Bdst = &Bs[wid * 2048];
  const size_t rstep8 = (size_t)8 * Kfull;

  f32x4 acc[4][4] = {};

  for (int k0 = 0; k0 < KH; k0 += 64) {
    __syncthreads();
#pragma unroll
    for (int cc = 0; cc < 4; ++cc)
      gll16(Ap + k0 + cc * rstep8, Adst + cc * 512);
#pragma unroll
    for (int cc = 0; cc < 4; ++cc)
      gll16(Bp + k0 + cc * rstep8, Bdst + cc * 512);
    __syncthreads();
#pragma unroll
    for (int kk = 0; kk < 2; ++kk) {
      bf8 af[4], bfr[4];
#pragma unroll
      for (int i = 0; i < 4; ++i) {
        const int row = wm + i * 16 + la;
        const int c8 = (kk * 4 + lg) ^ (row & 7);
        af[i] = asbf8(*(const u16x8*)(&As[row * 64 + c8 * 8]));
      }
#pragma unroll
      for (int j = 0; j < 4; ++j) {
        const int row = wn + j * 16 + la;
        const int c8 = (kk * 4 + lg) ^ (row & 7);
        bfr[j] = asbf8(*(const u16x8*)(&Bs[row * 64 + c8 * 8]));
      }
      __builtin_amdgcn_s_setprio(1);
#pragma unroll
      for (int i = 0; i < 4; ++i)
#pragma unroll
        for (int j = 0; j < 4; ++j)
          acc[i][j] = __builtin_amdgcn_mfma_f32_16x16x32_bf16(af[i], bfr[j],
                                                              acc[i][j], 0, 0, 0);
      __builtin_amdgcn_s_setprio(0);
    }
  }

#pragma unroll
  for (int i = 0; i < 4; ++i)
#pragma unroll
    for (int j = 0; j < 4; ++j)
#pragma unroll
      for (int r = 0; r < 4; ++r) {
        int row = m0 + wm + i * 16 + lg * 4 + r;
        int col = n0 + wn + j * 16 + la;
        C[(size_t)row * N + col] = f2b(acc[i][j][r]);
      }
}

// --- flash attention: LDS-shared KV, 8 waves = 4 q-tiles x 2 kv-halves ----

#define STEPL(buf, bb) do {                                          \
    const u16* p_ = &smem[(((h2) << 1) | (buf)) * 4096 + lane8];     \
    bf8 K0 = asbf8(*(const u16x8*)(p_));                             \
    bf8 K1 = asbf8(*(const u16x8*)(p_ + 512));                       \
    bf8 K2 = asbf8(*(const u16x8*)(p_ + 1024));                      \
    bf8 K3 = asbf8(*(const u16x8*)(p_ + 1536));                      \
    bf8 V0 = asbf8(*(const u16x8*)(p_ + 2048));                      \
    bf8 V1 = asbf8(*(const u16x8*)(p_ + 2560));                      \
    bf8 V2 = asbf8(*(const u16x8*)(p_ + 3072));                      \
    bf8 V3 = asbf8(*(const u16x8*)(p_ + 3584));                      \
    f32x16 s = {};                                                   \
    __builtin_amdgcn_s_setprio(1);                                   \
    s = MFMA32(K0, qf0, s);                                          \
    s = MFMA32(K1, qf1, s);                                          \
    s = MFMA32(K2, qf2, s);                                          \
    s = MFMA32(K3, qf3, s);                                          \
    __builtin_amdgcn_s_setprio(0);                                   \
    if ((bb) == kmax) {                                              \
      _Pragma("unroll") for (int r = 0; r < 16; ++r) {               \
        int kvr = (bb) * 32 + (r & 3) + 8 * (r >> 2) + 4 * hi;       \
        if (kvr > q0w + la) s[r] = -1e30f;                           \
      }                                                              \
    }                                                                \
    _Pragma("unroll") for (int r = 0; r < 16; ++r)                   \
      s[r] = ex2(s[r] - 32.0f);                                      \
    float z0 = s[0] + s[1],   z1 = s[2] + s[3];                      \
    float z2 = s[4] + s[5],   z3 = s[6] + s[7];                      \
    float z4 = s[8] + s[9],   z5 = s[10] + s[11];                    \
    float z6 = s[12] + s[13], z7 = s[14] + s[15];                    \
    l_run += ((z0 + z1) + (z2 + z3)) + ((z4 + z5) + (z6 + z7));      \
    u32 c0 = cvtpk(s[0], s[1]),   c1 = cvtpk(s[2], s[3]);            \
    u32 c2 = cvtpk(s[4], s[5]),   c3 = cvtpk(s[6], s[7]);            \
    u32 c4 = cvtpk(s[8], s[9]),   c5 = cvtpk(s[10], s[11]);          \
    u32 c6 = cvtpk(s[12], s[13]), c7 = cvtpk(s[14], s[15]);          \
    plswap(c0, c2); plswap(c1, c3); plswap(c4, c6); plswap(c5, c7);  \
    u32x4 t0; t0[0] = c0; t0[1] = c1; t0[2] = c2; t0[3] = c3;        \
    u32x4 t1; t1[0] = c4; t1[1] = c5; t1[2] = c6; t1[3] = c7;        \
    bf8 pa0 = __builtin_bit_cast(bf8, t0);                           \
    bf8 pa1 = __builtin_bit_cast(bf8, t1);                           \
    __builtin_amdgcn_s_setprio(1);                                   \
    o0 = MFMA32(pa0, V0, o0);                                        \
    o0 = MFMA32(pa1, V1, o0);                                        \
    o1 = MFMA32(pa0, V2, o1);                                        \
    o1 = MFMA32(pa1, V3, o1);                                        \
    __builtin_amdgcn_s_setprio(0);                                   \
  } while (0)

#define STG(bb, buf) do {                                            \
    u16* d_ = &smem[((((h2) << 1) | (buf)) * 4096) + sub * 512];     \
    gll16(Kg + (size_t)(bb) * 2048 + sub * 512 + lane8, d_);         \
    gll16(Vg + (size_t)(bb) * 2048 + sub * 512 + lane8, d_ + 2048);  \
  } while (0)

__global__ __launch_bounds__(512, 4) void attn_fwd(const u16* __restrict__ qkv,
                                                   const u16* __restrict__ Kf,
                                                   const u16* __restrict__ Vf,
                                                   u16* __restrict__ aout) {
  const int head = blockIdx.x;
  const int qb = 15 - (int)blockIdx.y;   // heavy q-blocks dispatch first
  const int Q0 = qb * 128;
  const int Kb = qb * 4;                 // kv-block index of Q0
  const int nb = Kb + 4;                 // kv blocks total (even)
  const int ha = nb >> 1;                // steps; half A: [0,ha), B: [ha,nb)
  const int kh = head >> 2;              // GROUPS = 4
  const int t = threadIdx.x;
  const int w = t >> 6, lane = t & 63;
  const int h2 = w >> 2;                 // kv half
  const int wq = w & 3;                  // q sub-tile
  const int sub = wq;                    // staging chunk
  const int la = lane & 31;
  const int hi = lane >> 5;
  const int lane8 = lane * 8;
  const int q0w = Q0 + 32 * wq;
  const int kmax = Kb + wq;              // this wave's diagonal kv-block

  __shared__ __align__(16) u16 smem[18432];
  __shared__ float lM[8][32];

  // Q B-fragments, prescaled by 0.125*log2(e) (base-2 softmax domain)
  bf8 qf0, qf1, qf2, qf3;
  {
    const u16* qp = qkv + (size_t)(q0w + la) * 3072 + head * 64 + hi * 8;
    const float SC = 0.125f * 1.44269504088896340736f;
#define QLOAD(dst, kk) do {                                          \
      u16x8 v = *(const u16x8*)(qp + (kk) * 16);                     \
      u16x8 sv;                                                      \
      _Pragma("unroll") for (int e = 0; e < 8; ++e)                  \
        sv[e] = f2b(b2f(v[e]) * SC);                                 \
      dst = asbf8(sv);                                               \
    } while (0)
    QLOAD(qf0, 0); QLOAD(qf1, 1); QLOAD(qf2, 2); QLOAD(qf3, 3);
#undef QLOAD
  }

  const u16* Kg = Kf + (size_t)kh * 131072;
  const u16* Vg = Vf + (size_t)kh * 131072;

  f32x16 o0 = {}, o1 = {};
  float l_run = 0.f;

  STG(h2 ? ha : 0, 0);
  __syncthreads();

  for (int i = 0; i < ha; ++i) {
    if (i + 1 < ha) STG(h2 ? (ha + i + 1) : (i + 1), (i + 1) & 1);
    const int bb = h2 ? (ha + i) : i;
    if (bb <= kmax) STEPL(i & 1, bb);
    __syncthreads();
  }

  {
    float lt = l_run + __shfl_xor(l_run, 32);
    if (lane < 32) lM[w][lane] = lt;
#pragma unroll
    for (int r = 0; r < 16; ++r) {
      int crow = (r & 3) + 8 * (r >> 2) + 4 * hi;
      smem[(w * 32 + crow) * 72 + la]      = f2b(o0[r]);
      smem[(w * 32 + crow) * 72 + la + 32] = f2b(o1[r]);
    }
  }
  __syncthreads();

#pragma unroll
  for (int it = 0; it < 2; ++it) {
    const int id = t + it * 512;
    const int q = id >> 3, d0 = (id & 7) * 8;
    const int wA = q >> 5, crow = q & 31;
    float inv = 1.0f / (lM[wA][crow] + lM[wA + 4][crow]);
    u16x8 a = *(const u16x8*)&smem[((wA)     * 32 + crow) * 72 + d0];
    u16x8 b = *(const u16x8*)&smem[((wA + 4) * 32 + crow) * 72 + d0];
    u16x8 outv;
#pragma unroll
    for (int j = 0; j < 8; ++j)
      outv[j] = f2b((b2f(a[j]) + b2f(b[j])) * inv);
    *(u16x8*)(aout + (size_t)(Q0 + q) * 2048 + head * 64 + d0) = outv;
  }
}

// ---------------- launch ----------------

extern "C" void kernel_launch(void* const* d_in, const int* in_sizes, int n_in,
                              void* d_out, int out_size, void* d_ws, size_t ws_size,
                              hipStream_t stream) {
  (void)in_sizes; (void)n_in; (void)out_size; (void)ws_size;
  const float* x  = (const float*)d_in[0];
  const float* wq = (const float*)d_in[1];
  const float* wk = (const float*)d_in[2];
  const float* wv = (const float*)d_in[3];
  const float* wo = (const float*)d_in[4];
  const float* cs = (const float*)d_in[5];
  const float* sn = (const float*)d_in[6];
  // d_in[7] = causal mask, implemented analytically

  u16* ws    = (u16*)d_ws;
  u16* xb    = ws;                         // [2048][2048] bf16 (later aout)
  u16* wqkvT = ws + 4194304;               // [3072][2048] bf16 (later Kf/Vf)
  u16* qkv   = ws + 10485760;              // [2048][3072] bf16; QKV partial z=0 in place
  u16* woT   = ws + 16777216;              // [2048][2048] bf16
  u16* ext   = ws + 20971520;              // [2048][3072] bf16: QKV partial z=1
  u16* Kf    = wqkvT;                      // [8][64][4][2][32][8] after QKV gemm
  u16* Vf    = wqkvT + 1048576;
  u16* aout  = xb;
  u16* op0   = qkv;                        // out-proj partials (qkv region free)
  u16* op1   = ext;

  xconv<<<4096, 256, 0, stream>>>(x, xb);
  wtrans<<<dim3(64, 64), 256, 0, stream>>>(wq, wqkvT, 2048, 2048);
  wtrans<<<dim3(16, 64), 256, 0, stream>>>(wk, wqkvT + (size_t)2048 * 2048, 512, 2048);
  wtrans<<<dim3(16, 64), 256, 0, stream>>>(wv, wqkvT + (size_t)2560 * 2048, 512, 2048);
  wtrans<<<dim3(64, 64), 256, 0, stream>>>(wo, woT, 2048, 2048);

  // QKV: [2048][3072], split-K x2 (768 blocks), BK=64
  gemm_sk<<<dim3(24, 16, 2), 256, 0, stream>>>(xb, wqkvT, qkv, ext, 3072, 2048, 1024);
  reduce_qkv<<<3072, 256, 0, stream>>>(qkv, ext, cs, sn);
  ktrans_f<<<512, 256, 0, stream>>>(qkv, Kf);
  vtrans_f<<<512, 256, 0, stream>>>(qkv, Vf);
  attn_fwd<<<dim3(32, 16), 512, 0, stream>>>(qkv, Kf, Vf, aout);
  // out-proj: [2048][2048], split-K x2 (512 blocks), BK=64
  gemm_sk<<<dim3(16, 16, 2), 256, 0, stream>>>(aout, woT, op0, op1, 2048, 2048, 1024);
  reduce_out<<<2048, 256, 0, stream>>>(op0, op1, (float*)d_out);
}

// Round 13
// 140.512 us; speedup vs baseline: 1.1792x; 1.0145x over previous
//
#include <hip/hip_runtime.h>

typedef unsigned short u16;
typedef unsigned u32;
typedef u16 u16x8 __attribute__((ext_vector_type(8)));
typedef u16 u16x4 __attribute__((ext_vector_type(4)));
typedef u32 u32x4 __attribute__((ext_vector_type(4)));
typedef __bf16 bf8 __attribute__((ext_vector_type(8)));
typedef float f32x4 __attribute__((ext_vector_type(4)));
typedef float f32x16 __attribute__((ext_vector_type(16)));

__device__ __forceinline__ u16 f2b(float f) {
  unsigned u = __float_as_uint(f);
  u += 0x7FFFu + ((u >> 16) & 1u);   // RNE
  return (u16)(u >> 16);
}
__device__ __forceinline__ float b2f(u16 h) {
  return __uint_as_float(((unsigned)h) << 16);
}
__device__ __forceinline__ bf8 asbf8(u16x8 v) {
  return __builtin_bit_cast(bf8, v);
}
__device__ __forceinline__ void gll16(const u16* g, u16* l) {
  __builtin_amdgcn_global_load_lds(
      (const __attribute__((address_space(1))) unsigned*)(g),
      (__attribute__((address_space(3))) unsigned*)(l), 16, 0, 0);
}
__device__ __forceinline__ u32 cvtpk(float lo, float hi) {
  u32 r;
  asm("v_cvt_pk_bf16_f32 %0, %1, %2" : "=v"(r) : "v"(lo), "v"(hi));
  return r;
}
// v_permlane32_swap_b32 a, b:  a.hi32lanes <-> b.lo32lanes
__device__ __forceinline__ void plswap(u32& a, u32& b) {
  asm("v_permlane32_swap_b32 %0, %1" : "+v"(a), "+v"(b));
}
__device__ __forceinline__ float ex2(float x) {
  return __builtin_amdgcn_exp2f(x);
}
#define MFMA32(A,B,C) __builtin_amdgcn_mfma_f32_32x32x16_bf16(A,B,C,0,0,0)

// ---------------- prep kernels ----------------

__global__ __launch_bounds__(256) void xconv(const float* __restrict__ x,
                                             u16* __restrict__ xb) {
  int i = (blockIdx.x * 256 + threadIdx.x) * 4;
  float4 v = *(const float4*)(x + i);
  u16x4 o;
  o[0] = f2b(v.x); o[1] = f2b(v.y); o[2] = f2b(v.z); o[3] = f2b(v.w);
  *(u16x4*)(xb + i) = o;
}

// in [K][N] f32  ->  out [N][K] bf16   (transpose + convert)
__global__ __launch_bounds__(256) void wtrans(const float* __restrict__ in,
                                              u16* __restrict__ out,
                                              int N, int K) {
  __shared__ float tile[32][33];
  int tx = threadIdx.x & 31, ty = threadIdx.x >> 5;
  int n0 = blockIdx.x * 32, k0 = blockIdx.y * 32;
#pragma unroll
  for (int yy = 0; yy < 32; yy += 8)
    tile[ty + yy][tx] = in[(size_t)(k0 + ty + yy) * N + n0 + tx];
  __syncthreads();
#pragma unroll
  for (int yy = 0; yy < 32; yy += 8)
    out[(size_t)(n0 + ty + yy) * K + k0 + tx] = f2b(tile[tx][ty + yy]);
}

// split-K reduce for qkv + fused RoPE. p0 (=qkv region) updated in place.
__global__ __launch_bounds__(256) void reduce_qkv(u16* __restrict__ p0,
                                                  const u16* __restrict__ p1,
                                                  const float* __restrict__ cs,
                                                  const float* __restrict__ sn) {
  int idx = blockIdx.x * 256 + threadIdx.x;      // 2048*384
  int s = idx / 384, c8 = (idx % 384) * 8;
  size_t base = (size_t)s * 3072 + c8;
  if (c8 < 2560) {                               // q or k head: RoPE pairs
    int hc = c8 & 63;
    if (hc >= 32) return;                        // partner handles
    u16x8 a0 = *(const u16x8*)(p0 + base);
    u16x8 a1 = *(const u16x8*)(p1 + base);
    u16x8 b0 = *(const u16x8*)(p0 + base + 32);
    u16x8 b1 = *(const u16x8*)(p1 + base + 32);
    u16x8 oa, ob;
#pragma unroll
    for (int e = 0; e < 8; ++e) {
      float va = b2f(a0[e]) + b2f(a1[e]);
      float vb = b2f(b0[e]) + b2f(b1[e]);
      float c1 = cs[s * 64 + hc + e],      s1 = sn[s * 64 + hc + e];
      float c2 = cs[s * 64 + hc + 32 + e], s2 = sn[s * 64 + hc + 32 + e];
      oa[e] = f2b(va * c1 - vb * s1);
      ob[e] = f2b(vb * c2 + va * s2);
    }
    *(u16x8*)(p0 + base)      = oa;
    *(u16x8*)(p0 + base + 32) = ob;
  } else {                                       // v: plain sum
    u16x8 a0 = *(const u16x8*)(p0 + base);
    u16x8 a1 = *(const u16x8*)(p1 + base);
    u16x8 o;
#pragma unroll
    for (int e = 0; e < 8; ++e) o[e] = f2b(b2f(a0[e]) + b2f(a1[e]));
    *(u16x8*)(p0 + base) = o;
  }
}

// split-K reduce for out-proj -> f32 d_out
__global__ __launch_bounds__(256) void reduce_out(const u16* __restrict__ p0,
                                                  const u16* __restrict__ p1,
                                                  float* __restrict__ out) {
  int idx = blockIdx.x * 256 + threadIdx.x;      // 2048*256
  size_t base = (size_t)idx * 8;
  u16x8 a0 = *(const u16x8*)(p0 + base);
  u16x8 a1 = *(const u16x8*)(p1 + base);
  float4 lo, hi;
  lo.x = b2f(a0[0]) + b2f(a1[0]); lo.y = b2f(a0[1]) + b2f(a1[1]);
  lo.z = b2f(a0[2]) + b2f(a1[2]); lo.w = b2f(a0[3]) + b2f(a1[3]);
  hi.x = b2f(a0[4]) + b2f(a1[4]); hi.y = b2f(a0[5]) + b2f(a1[5]);
  hi.z = b2f(a0[6]) + b2f(a1[6]); hi.w = b2f(a0[7]) + b2f(a1[7]);
  *(float4*)(out + base)     = lo;
  *(float4*)(out + base + 4) = hi;
}

// fused K/V -> fragment-major repack.
// blocks 0..511:  Kf[kh][b][j][hi][la][8]  = K[s][d]
// blocks 512..1023: Vf[kh][b][f][hi][la][8] = V^T fragments
__global__ __launch_bounds__(256) void kvtrans_f(const u16* __restrict__ qkv,
                                                 u16* __restrict__ Kf,
                                                 u16* __restrict__ Vf) {
  int bid = blockIdx.x;
  if (bid < 512) {
    int tid = bid * 256 + threadIdx.x;
    int s = tid >> 6, cc = tid & 63;
    int kh = cc >> 3, c = cc & 7;
    int j = c >> 1, hi = c & 1;
    int b = s >> 5, la = s & 31;
    u16x8 v = *(const u16x8*)(qkv + (size_t)s * 3072 + 2048 + cc * 8);
    *(u16x8*)(Kf + ((((size_t)(kh * 64 + b) * 4 + j) * 2 + hi) * 32 + la) * 8) = v;
  } else {
    int tid = (bid - 512) * 256 + threadIdx.x;
    int s = tid >> 6, cc = tid & 63;
    int kh = cc >> 3, c = cc & 7;
    int m = c >> 2, laB = (c & 3) * 8;
    int b = s >> 5, s5 = s & 31;
    int jj = s5 >> 4, hi = (s5 >> 3) & 1, e = s5 & 7;
    u16x8 v = *(const u16x8*)(qkv + (size_t)s * 3072 + 2560 + cc * 8);
    u16* dst = Vf + (((size_t)(kh * 64 + b) * 4 + m * 2 + jj) * 64 + hi * 32 + laB) * 8 + e;
#pragma unroll
    for (int i = 0; i < 8; ++i) dst[i * 8] = v[i];
  }
}

// ------- split-K GEMM, BK=64, XOR-swizzled LDS ----------------------------

__global__ __launch_bounds__(256) void gemm_sk(const u16* __restrict__ A,
                                               const u16* __restrict__ Bt,
                                               u16* __restrict__ C0,
                                               u16* __restrict__ C1,
                                               int N, int Kfull, int KH) {
  __shared__ __align__(16) u16 As[128 * 64];
  __shared__ __align__(16) u16 Bs[128 * 64];
  const int t = threadIdx.x;
  const int lane = t & 63, wid = t >> 6;
  const int wm = (wid >> 1) * 64, wn = (wid & 1) * 64;
  const int la = lane & 15, lg = lane >> 4;
  const int m0 = blockIdx.y * 128, n0 = blockIdx.x * 128;
  const int kbeg = blockIdx.z * KH;
  u16* C = blockIdx.z ? C1 : C0;

  const int srow0 = wid * 32 + (lane >> 3);
  const int scolsw = (((lane & 7) ^ (lane >> 3))) * 8;   // pre-swizzled col
  const u16* Ap = A + (size_t)(m0 + srow0) * Kfull + kbeg + scolsw;
  const u16* Bp = Bt + (size_t)(n0 + srow0) * Kfull + kbeg + scolsw;
  u16* Adst = &As[wid * 2048];
  u16* Bdst = &Bs[wid * 2048];
  const size_t rstep8 = (size_t)8 * Kfull;

  f32x4 acc[4][4] = {};

  for (int k0 = 0; k0 < KH; k0 += 64) {
    __syncthreads();
#pragma unroll
    for (int cc = 0; cc < 4; ++cc)
      gll16(Ap + k0 + cc * rstep8, Adst + cc * 512);
#pragma unroll
    for (int cc = 0; cc < 4; ++cc)
      gll16(Bp + k0 + cc * rstep8, Bdst + cc * 512);
    __syncthreads();
#pragma unroll
    for (int kk = 0; kk < 2; ++kk) {
      bf8 af[4], bfr[4];
#pragma unroll
      for (int i = 0; i < 4; ++i) {
        const int row = wm + i * 16 + la;
        const int c8 = (kk * 4 + lg) ^ (row & 7);
        af[i] = asbf8(*(const u16x8*)(&As[row * 64 + c8 * 8]));
      }
#pragma unroll
      for (int j = 0; j < 4; ++j) {
        const int row = wn + j * 16 + la;
        const int c8 = (kk * 4 + lg) ^ (row & 7);
        bfr[j] = asbf8(*(const u16x8*)(&Bs[row * 64 + c8 * 8]));
      }
      __builtin_amdgcn_s_setprio(1);
#pragma unroll
      for (int i = 0; i < 4; ++i)
#pragma unroll
        for (int j = 0; j < 4; ++j)
          acc[i][j] = __builtin_amdgcn_mfma_f32_16x16x32_bf16(af[i], bfr[j],
                                                              acc[i][j], 0, 0, 0);
      __builtin_amdgcn_s_setprio(0);
    }
  }

#pragma unroll
  for (int i = 0; i < 4; ++i)
#pragma unroll
    for (int j = 0; j < 4; ++j)
#pragma unroll
      for (int r = 0; r < 4; ++r) {
        int row = m0 + wm + i * 16 + lg * 4 + r;
        int col = n0 + wn + j * 16 + la;
        C[(size_t)row * N + col] = f2b(acc[i][j][r]);
      }
}

// --- flash attention: LDS-shared KV, 4 waves = 2 q-tiles x 2 kv-halves ----
// Block = (head, 64 q rows), 256 threads, 1024 blocks = 4/CU resident ->
// barrier drains of independent blocks overlap (m114 implicit overlap).
// Static-max softmax (shared m=32); 2-half merge = plain sum in LDS.

#define STEPL(buf, bb) do {                                          \
    const u16* p_ = &smem[(((h2) << 1) | (buf)) * 4096 + lane8];     \
    bf8 K0 = asbf8(*(const u16x8*)(p_));                             \
    bf8 K1 = asbf8(*(const u16x8*)(p_ + 512));                       \
    bf8 K2 = asbf8(*(const u16x8*)(p_ + 1024));                      \
    bf8 K3 = asbf8(*(const u16x8*)(p_ + 1536));                      \
    bf8 V0 = asbf8(*(const u16x8*)(p_ + 2048));                      \
    bf8 V1 = asbf8(*(const u16x8*)(p_ + 2560));                      \
    bf8 V2 = asbf8(*(const u16x8*)(p_ + 3072));                      \
    bf8 V3 = asbf8(*(const u16x8*)(p_ + 3584));                      \
    f32x16 s = {};                                                   \
    __builtin_amdgcn_s_setprio(1);                                   \
    s = MFMA32(K0, qf0, s);                                          \
    s = MFMA32(K1, qf1, s);                                          \
    s = MFMA32(K2, qf2, s);                                          \
    s = MFMA32(K3, qf3, s);                                          \
    __builtin_amdgcn_s_setprio(0);                                   \
    if ((bb) == kmax) {                                              \
      _Pragma("unroll") for (int r = 0; r < 16; ++r) {               \
        int kvr = (bb) * 32 + (r & 3) + 8 * (r >> 2) + 4 * hi;       \
        if (kvr > q0w + la) s[r] = -1e30f;                           \
      }                                                              \
    }                                                                \
    _Pragma("unroll") for (int r = 0; r < 16; ++r)                   \
      s[r] = ex2(s[r] - 32.0f);                                      \
    float z0 = s[0] + s[1],   z1 = s[2] + s[3];                      \
    float z2 = s[4] + s[5],   z3 = s[6] + s[7];                      \
    float z4 = s[8] + s[9],   z5 = s[10] + s[11];                    \
    float z6 = s[12] + s[13], z7 = s[14] + s[15];                    \
    l_run += ((z0 + z1) + (z2 + z3)) + ((z4 + z5) + (z6 + z7));      \
    u32 c0 = cvtpk(s[0], s[1]),   c1 = cvtpk(s[2], s[3]);            \
    u32 c2 = cvtpk(s[4], s[5]),   c3 = cvtpk(s[6], s[7]);            \
    u32 c4 = cvtpk(s[8], s[9]),   c5 = cvtpk(s[10], s[11]);          \
    u32 c6 = cvtpk(s[12], s[13]), c7 = cvtpk(s[14], s[15]);          \
    plswap(c0, c2); plswap(c1, c3); plswap(c4, c6); plswap(c5, c7);  \
    u32x4 t0; t0[0] = c0; t0[1] = c1; t0[2] = c2; t0[3] = c3;        \
    u32x4 t1; t1[0] = c4; t1[1] = c5; t1[2] = c6; t1[3] = c7;        \
    bf8 pa0 = __builtin_bit_cast(bf8, t0);                           \
    bf8 pa1 = __builtin_bit_cast(bf8, t1);                           \
    __builtin_amdgcn_s_setprio(1);                                   \
    o0 = MFMA32(pa0, V0, o0);                                        \
    o0 = MFMA32(pa1, V1, o0);                                        \
    o1 = MFMA32(pa0, V2, o1);                                        \
    o1 = MFMA32(pa1, V3, o1);                                        \
    __builtin_amdgcn_s_setprio(0);                                   \
  } while (0)

// wave w stages its own half's block: 4 x gll16 (K 2x512, V 2x512)
#define STG(bb, buf) do {                                            \
    u16* d_ = &smem[((((h2) << 1) | (buf)) * 4096) + wq * 1024];     \
    const u16* kp_ = Kg + (size_t)(bb) * 2048 + wq * 1024 + lane8;   \
    const u16* vp_ = Vg + (size_t)(bb) * 2048 + wq * 1024 + lane8;   \
    gll16(kp_, d_);                                                  \
    gll16(kp_ + 512, d_ + 512);                                      \
    gll16(vp_, d_ + 2048);                                           \
    gll16(vp_ + 512, d_ + 2560);                                     \
  } while (0)

__global__ __launch_bounds__(256, 4) void attn_fwd(const u16* __restrict__ qkv,
                                                   const u16* __restrict__ Kf,
                                                   const u16* __restrict__ Vf,
                                                   u16* __restrict__ aout) {
  const int head = blockIdx.x;
  const int qt = 31 - (int)blockIdx.y;   // heavy q-blocks dispatch first
  const int Q0 = qt * 64;
  const int Kb = qt * 2;                 // kv-block index of Q0
  const int nb = Kb + 2;                 // kv blocks total (even)
  const int ha = nb >> 1;                // steps; half A: [0,ha), B: [ha,nb)
  const int kh = head >> 2;              // GROUPS = 4
  const int t = threadIdx.x;
  const int w = t >> 6, lane = t & 63;
  const int h2 = w >> 1;                 // kv half
  const int wq = w & 1;                  // q sub-tile
  const int la = lane & 31;
  const int hi = lane >> 5;
  const int lane8 = lane * 8;
  const int q0w = Q0 + 32 * wq;
  const int kmax = Kb + wq;              // this wave's diagonal kv-block

  // staging: 4 slots (half,buf) x 4096 u16 (K 2048 | V 2048) = 32 KB
  // merge overlay: [4][32][72] u16 = 9216 u16, reused post-loop
  __shared__ __align__(16) u16 smem[16384];
  __shared__ float lM[4][32];

  // Q B-fragments, prescaled by 0.125*log2(e) (base-2 softmax domain)
  bf8 qf0, qf1, qf2, qf3;
  {
    const u16* qp = qkv + (size_t)(q0w + la) * 3072 + head * 64 + hi * 8;
    const float SC = 0.125f * 1.44269504088896340736f;
#define QLOAD(dst, kk) do {                                          \
      u16x8 v = *(const u16x8*)(qp + (kk) * 16);                     \
      u16x8 sv;                                                      \
      _Pragma("unroll") for (int e = 0; e < 8; ++e)                  \
        sv[e] = f2b(b2f(v[e]) * SC);                                 \
      dst = asbf8(sv);                                               \
    } while (0)
    QLOAD(qf0, 0); QLOAD(qf1, 1); QLOAD(qf2, 2); QLOAD(qf3, 3);
#undef QLOAD
  }

  const u16* Kg = Kf + (size_t)kh * 131072;
  const u16* Vg = Vf + (size_t)kh * 131072;

  f32x16 o0 = {}, o1 = {};
  float l_run = 0.f;

  STG(h2 ? ha : 0, 0);
  __syncthreads();

  for (int i = 0; i < ha; ++i) {
    if (i + 1 < ha) STG(h2 ? (ha + i + 1) : (i + 1), (i + 1) & 1);
    const int bb = h2 ? (ha + i) : i;
    if (bb <= kmax) STEPL(i & 1, bb);
    __syncthreads();
  }

  // publish partials: l (half-combined) and O (bf16) into overlay
  {
    float lt = l_run + __shfl_xor(l_run, 32);
    if (lane < 32) lM[w][lane] = lt;
#pragma unroll
    for (int r = 0; r < 16; ++r) {
      int crow = (r & 3) + 8 * (r >> 2) + 4 * hi;
      smem[(w * 32 + crow) * 72 + la]      = f2b(o0[r]);
      smem[(w * 32 + crow) * 72 + la + 32] = f2b(o1[r]);
    }
  }
  __syncthreads();

  // merge: plain sums (shared m=32). 512 items (64 q x 8 d-chunks)
#pragma unroll
  for (int it = 0; it < 2; ++it) {
    const int id = t + it * 256;
    const int q = id >> 3, d0 = (id & 7) * 8;
    const int wA = q >> 5, crow = q & 31;
    float inv = 1.0f / (lM[wA][crow] + lM[wA + 2][crow]);
    u16x8 a = *(const u16x8*)&smem[((wA)     * 32 + crow) * 72 + d0];
    u16x8 b = *(const u16x8*)&smem[((wA + 2) * 32 + crow) * 72 + d0];
    u16x8 outv;
#pragma unroll
    for (int j = 0; j < 8; ++j)
      outv[j] = f2b((b2f(a[j]) + b2f(b[j])) * inv);
    *(u16x8*)(aout + (size_t)(Q0 + q) * 2048 + head * 64 + d0) = outv;
  }
}

// ---------------- launch ----------------

extern "C" void kernel_launch(void* const* d_in, const int* in_sizes, int n_in,
                              void* d_out, int out_size, void* d_ws, size_t ws_size,
                              hipStream_t stream) {
  (void)in_sizes; (void)n_in; (void)out_size; (void)ws_size;
  const float* x  = (const float*)d_in[0];
  const float* wq = (const float*)d_in[1];
  const float* wk = (const float*)d_in[2];
  const float* wv = (const float*)d_in[3];
  const float* wo = (const float*)d_in[4];
  const float* cs = (const float*)d_in[5];
  const float* sn = (const float*)d_in[6];
  // d_in[7] = causal mask, implemented analytically

  u16* ws    = (u16*)d_ws;
  u16* xb    = ws;                         // [2048][2048] bf16 (later aout)
  u16* wqkvT = ws + 4194304;               // [3072][2048] bf16 (later Kf/Vf)
  u16* qkv   = ws + 10485760;              // [2048][3072] bf16; QKV partial z=0 in place
  u16* woT   = ws + 16777216;              // [2048][2048] bf16
  u16* ext   = ws + 20971520;              // [2048][3072] bf16: QKV partial z=1
  u16* Kf    = wqkvT;                      // [8][64][4][2][32][8] after QKV gemm
  u16* Vf    = wqkvT + 1048576;
  u16* aout  = xb;
  u16* op0   = qkv;                        // out-proj partials (qkv region free)
  u16* op1   = ext;

  xconv<<<4096, 256, 0, stream>>>(x, xb);
  wtrans<<<dim3(64, 64), 256, 0, stream>>>(wq, wqkvT, 2048, 2048);
  wtrans<<<dim3(16, 64), 256, 0, stream>>>(wk, wqkvT + (size_t)2048 * 2048, 512, 2048);
  wtrans<<<dim3(16, 64), 256, 0, stream>>>(wv, wqkvT + (size_t)2560 * 2048, 512, 2048);
  wtrans<<<dim3(64, 64), 256, 0, stream>>>(wo, woT, 2048, 2048);

  // QKV: [2048][3072], split-K x2 (768 blocks), BK=64
  gemm_sk<<<dim3(24, 16, 2), 256, 0, stream>>>(xb, wqkvT, qkv, ext, 3072, 2048, 1024);
  reduce_qkv<<<3072, 256, 0, stream>>>(qkv, ext, cs, sn);
  kvtrans_f<<<1024, 256, 0, stream>>>(qkv, Kf, Vf);
  attn_fwd<<<dim3(32, 32), 256, 0, stream>>>(qkv, Kf, Vf, aout);
  // out-proj: [2048][2048], split-K x2 (512 blocks), BK=64
  gemm_sk<<<dim3(16, 16, 2), 256, 0, stream>>>(aout, woT, op0, op1, 2048, 2048, 1024);
  reduce_out<<<2048, 256, 0, stream>>>(op0, op1, (float*)d_out);
}

// Round 14
// 138.002 us; speedup vs baseline: 1.2007x; 1.0182x over previous
//
#include <hip/hip_runtime.h>

typedef unsigned short u16;
typedef unsigned u32;
typedef u16 u16x8 __attribute__((ext_vector_type(8)));
typedef u16 u16x4 __attribute__((ext_vector_type(4)));
typedef u32 u32x4 __attribute__((ext_vector_type(4)));
typedef __bf16 bf8 __attribute__((ext_vector_type(8)));
typedef float f32x4 __attribute__((ext_vector_type(4)));
typedef float f32x16 __attribute__((ext_vector_type(16)));

__device__ __forceinline__ u16 f2b(float f) {
  unsigned u = __float_as_uint(f);
  u += 0x7FFFu + ((u >> 16) & 1u);   // RNE
  return (u16)(u >> 16);
}
__device__ __forceinline__ float b2f(u16 h) {
  return __uint_as_float(((unsigned)h) << 16);
}
__device__ __forceinline__ bf8 asbf8(u16x8 v) {
  return __builtin_bit_cast(bf8, v);
}
__device__ __forceinline__ void gll16(const u16* g, u16* l) {
  __builtin_amdgcn_global_load_lds(
      (const __attribute__((address_space(1))) unsigned*)(g),
      (__attribute__((address_space(3))) unsigned*)(l), 16, 0, 0);
}
__device__ __forceinline__ u32 cvtpk(float lo, float hi) {
  u32 r;
  asm("v_cvt_pk_bf16_f32 %0, %1, %2" : "=v"(r) : "v"(lo), "v"(hi));
  return r;
}
// v_permlane32_swap_b32 a, b:  a.hi32lanes <-> b.lo32lanes
__device__ __forceinline__ void plswap(u32& a, u32& b) {
  asm("v_permlane32_swap_b32 %0, %1" : "+v"(a), "+v"(b));
}
__device__ __forceinline__ float ex2(float x) {
  return __builtin_amdgcn_exp2f(x);
}
#define MFMA32(A,B,C) __builtin_amdgcn_mfma_f32_32x32x16_bf16(A,B,C,0,0,0)

// ---------------- prep kernels ----------------

__global__ __launch_bounds__(256) void xconv(const float* __restrict__ x,
                                             u16* __restrict__ xb) {
  int i = (blockIdx.x * 256 + threadIdx.x) * 4;
  float4 v = *(const float4*)(x + i);
  u16x4 o;
  o[0] = f2b(v.x); o[1] = f2b(v.y); o[2] = f2b(v.z); o[3] = f2b(v.w);
  *(u16x4*)(xb + i) = o;
}

// in [K][N] f32  ->  out [N][K] bf16   (transpose + convert)
__global__ __launch_bounds__(256) void wtrans(const float* __restrict__ in,
                                              u16* __restrict__ out,
                                              int N, int K) {
  __shared__ float tile[32][33];
  int tx = threadIdx.x & 31, ty = threadIdx.x >> 5;
  int n0 = blockIdx.x * 32, k0 = blockIdx.y * 32;
#pragma unroll
  for (int yy = 0; yy < 32; yy += 8)
    tile[ty + yy][tx] = in[(size_t)(k0 + ty + yy) * N + n0 + tx];
  __syncthreads();
#pragma unroll
  for (int yy = 0; yy < 32; yy += 8)
    out[(size_t)(n0 + ty + yy) * K + k0 + tx] = f2b(tile[tx][ty + yy]);
}

// split-K reduce + RoPE + fused KV fragment repack.
//   Q cols  -> RoPE -> qkv (in place on p0)
//   K cols  -> RoPE -> Kf fragment-major  (qkv K region left untouched)
//   V cols  -> sum  -> Vf fragment-major
__global__ __launch_bounds__(256) void reduce_qkv(u16* __restrict__ p0,
                                                  const u16* __restrict__ p1,
                                                  u16* __restrict__ Kf,
                                                  u16* __restrict__ Vf,
                                                  const float* __restrict__ cs,
                                                  const float* __restrict__ sn) {
  int idx = blockIdx.x * 256 + threadIdx.x;      // 2048*384
  int s = idx / 384, c8 = (idx % 384) * 8;
  size_t base = (size_t)s * 3072 + c8;
  if (c8 < 2560) {                               // q or k head: RoPE pairs
    int hc = c8 & 63;
    if (hc >= 32) return;                        // partner handles
    u16x8 a0 = *(const u16x8*)(p0 + base);
    u16x8 a1 = *(const u16x8*)(p1 + base);
    u16x8 b0 = *(const u16x8*)(p0 + base + 32);
    u16x8 b1 = *(const u16x8*)(p1 + base + 32);
    u16x8 oa, ob;
#pragma unroll
    for (int e = 0; e < 8; ++e) {
      float va = b2f(a0[e]) + b2f(a1[e]);
      float vb = b2f(b0[e]) + b2f(b1[e]);
      float c1 = cs[s * 64 + hc + e],      s1 = sn[s * 64 + hc + e];
      float c2 = cs[s * 64 + hc + 32 + e], s2 = sn[s * 64 + hc + 32 + e];
      oa[e] = f2b(va * c1 - vb * s1);
      ob[e] = f2b(vb * c2 + va * s2);
    }
    if (c8 < 2048) {                             // Q: back to qkv
      *(u16x8*)(p0 + base)      = oa;
      *(u16x8*)(p0 + base + 32) = ob;
    } else {                                     // K: to fragment-major Kf
      int kh = (c8 - 2048) >> 6;
      int d0 = hc;                               // < 32, multiple of 8
      int b = s >> 5, la = s & 31;
      int j0 = d0 >> 4, hi0 = (d0 >> 3) & 1;
      size_t f0 = ((((size_t)(kh * 64 + b) * 4 + j0) * 2 + hi0) * 32 + la) * 8;
      size_t f1 = ((((size_t)(kh * 64 + b) * 4 + j0 + 2) * 2 + hi0) * 32 + la) * 8;
      *(u16x8*)(Kf + f0) = oa;
      *(u16x8*)(Kf + f1) = ob;
    }
  } else {                                       // V: sum -> Vf fragments
    u16x8 a0 = *(const u16x8*)(p0 + base);
    u16x8 a1 = *(const u16x8*)(p1 + base);
    int c = c8 - 2560;
    int kh = c >> 6, d0 = c & 63;
    int m = d0 >> 5, la0 = d0 & 31;
    int b = s >> 5, s5 = s & 31;
    int jj = s5 >> 4, hi = (s5 >> 3) & 1, e = s5 & 7;
    u16* dst = Vf + (((size_t)(kh * 64 + b) * 4 + m * 2 + jj) * 64 + hi * 32 + la0) * 8 + e;
#pragma unroll
    for (int i = 0; i < 8; ++i)
      dst[i * 8] = f2b(b2f(a0[i]) + b2f(a1[i]));
  }
}

// split-K reduce for out-proj -> f32 d_out
__global__ __launch_bounds__(256) void reduce_out(const u16* __restrict__ p0,
                                                  const u16* __restrict__ p1,
                                                  float* __restrict__ out) {
  int idx = blockIdx.x * 256 + threadIdx.x;      // 2048*256
  size_t base = (size_t)idx * 8;
  u16x8 a0 = *(const u16x8*)(p0 + base);
  u16x8 a1 = *(const u16x8*)(p1 + base);
  float4 lo, hi;
  lo.x = b2f(a0[0]) + b2f(a1[0]); lo.y = b2f(a0[1]) + b2f(a1[1]);
  lo.z = b2f(a0[2]) + b2f(a1[2]); lo.w = b2f(a0[3]) + b2f(a1[3]);
  hi.x = b2f(a0[4]) + b2f(a1[4]); hi.y = b2f(a0[5]) + b2f(a1[5]);
  hi.z = b2f(a0[6]) + b2f(a1[6]); hi.w = b2f(a0[7]) + b2f(a1[7]);
  *(float4*)(out + base)     = lo;
  *(float4*)(out + base + 4) = hi;
}

// ------- split-K GEMM, BK=64, XOR-swizzled LDS ----------------------------

__global__ __launch_bounds__(256) void gemm_sk(const u16* __restrict__ A,
                                               const u16* __restrict__ Bt,
                                               u16* __restrict__ C0,
                                               u16* __restrict__ C1,
                                               int N, int Kfull, int KH) {
  __shared__ __align__(16) u16 As[128 * 64];
  __shared__ __align__(16) u16 Bs[128 * 64];
  const int t = threadIdx.x;
  const int lane = t & 63, wid = t >> 6;
  const int wm = (wid >> 1) * 64, wn = (wid & 1) * 64;
  const int la = lane & 15, lg = lane >> 4;
  const int m0 = blockIdx.y * 128, n0 = blockIdx.x * 128;
  const int kbeg = blockIdx.z * KH;
  u16* C = blockIdx.z ? C1 : C0;

  const int srow0 = wid * 32 + (lane >> 3);
  const int scolsw = (((lane & 7) ^ (lane >> 3))) * 8;   // pre-swizzled col
  const u16* Ap = A + (size_t)(m0 + srow0) * Kfull + kbeg + scolsw;
  const u16* Bp = Bt + (size_t)(n0 + srow0) * Kfull + kbeg + scolsw;
  u16* Adst = &As[wid * 2048];
  u16* Bdst = &Bs[wid * 2048];
  const size_t rstep8 = (size_t)8 * Kfull;

  f32x4 acc[4][4] = {};

  for (int k0 = 0; k0 < KH; k0 += 64) {
    __syncthreads();
#pragma unroll
    for (int cc = 0; cc < 4; ++cc)
      gll16(Ap + k0 + cc * rstep8, Adst + cc * 512);
#pragma unroll
    for (int cc = 0; cc < 4; ++cc)
      gll16(Bp + k0 + cc * rstep8, Bdst + cc * 512);
    __syncthreads();
#pragma unroll
    for (int kk = 0; kk < 2; ++kk) {
      bf8 af[4], bfr[4];
#pragma unroll
      for (int i = 0; i < 4; ++i) {
        const int row = wm + i * 16 + la;
        const int c8 = (kk * 4 + lg) ^ (row & 7);
        af[i] = asbf8(*(const u16x8*)(&As[row * 64 + c8 * 8]));
      }
#pragma unroll
      for (int j = 0; j < 4; ++j) {
        const int row = wn + j * 16 + la;
        const int c8 = (kk * 4 + lg) ^ (row & 7);
        bfr[j] = asbf8(*(const u16x8*)(&Bs[row * 64 + c8 * 8]));
      }
      __builtin_amdgcn_s_setprio(1);
#pragma unroll
      for (int i = 0; i < 4; ++i)
#pragma unroll
        for (int j = 0; j < 4; ++j)
          acc[i][j] = __builtin_amdgcn_mfma_f32_16x16x32_bf16(af[i], bfr[j],
                                                              acc[i][j], 0, 0, 0);
      __builtin_amdgcn_s_setprio(0);
    }
  }

#pragma unroll
  for (int i = 0; i < 4; ++i)
#pragma unroll
    for (int j = 0; j < 4; ++j)
#pragma unroll
      for (int r = 0; r < 4; ++r) {
        int row = m0 + wm + i * 16 + lg * 4 + r;
        int col = n0 + wn + j * 16 + la;
        C[(size_t)row * N + col] = f2b(acc[i][j][r]);
      }
}

// --- flash attention: LDS-shared KV, 64-kv steps, 2 q-tiles x 2 halves ----
// Block = (head, 64 q rows), 256 threads. Per step each half stages ONE
// 64-kv fragment-major block (16KB) double-buffered; step = 2 sequential
// 32-kv groups -> barrier-pairs per block halve vs 32-kv steps.
// Static-max softmax (shared m=32); 2-half merge = plain LDS sum.

#define GROUPG(g, bb, base_) do {                                    \
    const int kvb_ = (bb) * 64 + (g) * 32;                           \
    if (kvb_ <= q0w + 31) {                                          \
      const u16* pk_ = (base_) + (g) * 2048;                         \
      const u16* pv_ = (base_) + 4096 + (g) * 2048;                  \
      bf8 K0 = asbf8(*(const u16x8*)(pk_));                          \
      bf8 K1 = asbf8(*(const u16x8*)(pk_ + 512));                    \
      bf8 K2 = asbf8(*(const u16x8*)(pk_ + 1024));                   \
      bf8 K3 = asbf8(*(const u16x8*)(pk_ + 1536));                   \
      bf8 V0 = asbf8(*(const u16x8*)(pv_));                          \
      bf8 V1 = asbf8(*(const u16x8*)(pv_ + 512));                    \
      bf8 V2 = asbf8(*(const u16x8*)(pv_ + 1024));                   \
      bf8 V3 = asbf8(*(const u16x8*)(pv_ + 1536));                   \
      f32x16 s = {};                                                 \
      __builtin_amdgcn_s_setprio(1);                                 \
      s = MFMA32(K0, qf0, s);                                        \
      s = MFMA32(K1, qf1, s);                                        \
      s = MFMA32(K2, qf2, s);                                        \
      s = MFMA32(K3, qf3, s);                                        \
      __builtin_amdgcn_s_setprio(0);                                 \
      if ((bb) == nb64 - 1) {                                        \
        _Pragma("unroll") for (int r = 0; r < 16; ++r) {             \
          int kvr = kvb_ + (r & 3) + 8 * (r >> 2) + 4 * hi;          \
          if (kvr > q0w + la) s[r] = -1e30f;                         \
        }                                                            \
      }                                                              \
      _Pragma("unroll") for (int r = 0; r < 16; ++r)                 \
        s[r] = ex2(s[r] - 32.0f);                                    \
      float z0 = s[0] + s[1],   z1 = s[2] + s[3];                    \
      float z2 = s[4] + s[5],   z3 = s[6] + s[7];                    \
      float z4 = s[8] + s[9],   z5 = s[10] + s[11];                  \
      float z6 = s[12] + s[13], z7 = s[14] + s[15];                  \
      l_run += ((z0 + z1) + (z2 + z3)) + ((z4 + z5) + (z6 + z7));    \
      u32 c0 = cvtpk(s[0], s[1]),   c1 = cvtpk(s[2], s[3]);          \
      u32 c2 = cvtpk(s[4], s[5]),   c3 = cvtpk(s[6], s[7]);          \
      u32 c4 = cvtpk(s[8], s[9]),   c5 = cvtpk(s[10], s[11]);        \
      u32 c6 = cvtpk(s[12], s[13]), c7 = cvtpk(s[14], s[15]);        \
      plswap(c0, c2); plswap(c1, c3); plswap(c4, c6); plswap(c5, c7);\
      u32x4 t0; t0[0] = c0; t0[1] = c1; t0[2] = c2; t0[3] = c3;      \
      u32x4 t1; t1[0] = c4; t1[1] = c5; t1[2] = c6; t1[3] = c7;      \
      bf8 pa0 = __builtin_bit_cast(bf8, t0);                         \
      bf8 pa1 = __builtin_bit_cast(bf8, t1);                         \
      __builtin_amdgcn_s_setprio(1);                                 \
      o0 = MFMA32(pa0, V0, o0);                                      \
      o0 = MFMA32(pa1, V1, o0);                                      \
      o1 = MFMA32(pa0, V2, o1);                                      \
      o1 = MFMA32(pa1, V3, o1);                                      \
      __builtin_amdgcn_s_setprio(0);                                 \
    }                                                                \
  } while (0)

#define STEPL(buf, bb) do {                                          \
    const u16* base_ = &smem[((((h2) << 1) | (buf)) * 8192) + lane8];\
    GROUPG(0, bb, base_);                                            \
    GROUPG(1, bb, base_);                                            \
  } while (0)

// wave stages half its half's 64-kv block: 8 x gll16 (K 4x512, V 4x512)
#define STG(bb, buf) do {                                            \
    u16* d_ = &smem[((((h2) << 1) | (buf)) * 8192) + wq * 2048];     \
    const u16* kp_ = Kg + (size_t)(bb) * 4096 + wq * 2048 + lane8;   \
    const u16* vp_ = Vg + (size_t)(bb) * 4096 + wq * 2048 + lane8;   \
    gll16(kp_, d_);                                                  \
    gll16(kp_ + 512, d_ + 512);                                      \
    gll16(kp_ + 1024, d_ + 1024);                                    \
    gll16(kp_ + 1536, d_ + 1536);                                    \
    gll16(vp_, d_ + 4096);                                           \
    gll16(vp_ + 512, d_ + 4608);                                     \
    gll16(vp_ + 1024, d_ + 5120);                                    \
    gll16(vp_ + 1536, d_ + 5632);                                    \
  } while (0)

__global__ __launch_bounds__(256, 2) void attn_fwd(const u16* __restrict__ qkv,
                                                   const u16* __restrict__ Kf,
                                                   const u16* __restrict__ Vf,
                                                   u16* __restrict__ aout) {
  const int head = blockIdx.x;
  const int qt = 31 - (int)blockIdx.y;   // heavy q-blocks dispatch first
  const int Q0 = qt * 64;
  const int nb64 = qt + 1;               // 64-kv blocks in causal span
  const int haA = (nb64 + 1) >> 1;       // half A count (>= half B)
  const int haB = nb64 >> 1;
  const int kh = head >> 2;              // GROUPS = 4
  const int t = threadIdx.x;
  const int w = t >> 6, lane = t & 63;
  const int h2 = w >> 1;                 // kv half
  const int wq = w & 1;                  // q sub-tile / staging sub
  const int la = lane & 31;
  const int hi = lane >> 5;
  const int lane8 = lane * 8;
  const int q0w = Q0 + 32 * wq;
  const int myn = h2 ? haB : haA;
  const int mybase = h2 ? haA : 0;

  // staging: 4 slots (half,buf) x 8192 u16 (K 4096 | V 4096) = 64 KB
  // merge overlay: [4][32][72] u16 = 9216 u16, reused post-loop
  __shared__ __align__(16) u16 smem[32768];
  __shared__ float lM[4][32];

  // Q B-fragments, prescaled by 0.125*log2(e) (base-2 softmax domain)
  bf8 qf0, qf1, qf2, qf3;
  {
    const u16* qp = qkv + (size_t)(q0w + la) * 3072 + head * 64 + hi * 8;
    const float SC = 0.125f * 1.44269504088896340736f;
#define QLOAD(dst, kk) do {                                          \
      u16x8 v = *(const u16x8*)(qp + (kk) * 16);                     \
      u16x8 sv;                                                      \
      _Pragma("unroll") for (int e = 0; e < 8; ++e)                  \
        sv[e] = f2b(b2f(v[e]) * SC);                                 \
      dst = asbf8(sv);                                               \
    } while (0)
    QLOAD(qf0, 0); QLOAD(qf1, 1); QLOAD(qf2, 2); QLOAD(qf3, 3);
#undef QLOAD
  }

  const u16* Kg = Kf + (size_t)kh * 131072;
  const u16* Vg = Vf + (size_t)kh * 131072;

  f32x16 o0 = {}, o1 = {};
  float l_run = 0.f;

  if (myn > 0) STG(mybase, 0);
  __syncthreads();

  for (int i = 0; i < haA; ++i) {
    if (i + 1 < myn) STG(mybase + i + 1, (i + 1) & 1);
    if (i < myn) STEPL(i & 1, mybase + i);
    __syncthreads();
  }

  // publish partials: l (half-combined) and O (bf16) into overlay
  {
    float lt = l_run + __shfl_xor(l_run, 32);
    if (lane < 32) lM[w][lane] = lt;
#pragma unroll
    for (int r = 0; r < 16; ++r) {
      int crow = (r & 3) + 8 * (r >> 2) + 4 * hi;
      smem[(w * 32 + crow) * 72 + la]      = f2b(o0[r]);
      smem[(w * 32 + crow) * 72 + la + 32] = f2b(o1[r]);
    }
  }
  __syncthreads();

  // merge: plain sums (shared m=32). 512 items (64 q x 8 d-chunks)
#pragma unroll
  for (int it = 0; it < 2; ++it) {
    const int id = t + it * 256;
    const int q = id >> 3, d0 = (id & 7) * 8;
    const int wA = q >> 5, crow = q & 31;
    float inv = 1.0f / (lM[wA][crow] + lM[wA + 2][crow]);
    u16x8 a = *(const u16x8*)&smem[((wA)     * 32 + crow) * 72 + d0];
    u16x8 b = *(const u16x8*)&smem[((wA + 2) * 32 + crow) * 72 + d0];
    u16x8 outv;
#pragma unroll
    for (int j = 0; j < 8; ++j)
      outv[j] = f2b((b2f(a[j]) + b2f(b[j])) * inv);
    *(u16x8*)(aout + (size_t)(Q0 + q) * 2048 + head * 64 + d0) = outv;
  }
}

// ---------------- launch ----------------

extern "C" void kernel_launch(void* const* d_in, const int* in_sizes, int n_in,
                              void* d_out, int out_size, void* d_ws, size_t ws_size,
                              hipStream_t stream) {
  (void)in_sizes; (void)n_in; (void)out_size; (void)ws_size;
  const float* x  = (const float*)d_in[0];
  const float* wq = (const float*)d_in[1];
  const float* wk = (const float*)d_in[2];
  const float* wv = (const float*)d_in[3];
  const float* wo = (const float*)d_in[4];
  const float* cs = (const float*)d_in[5];
  const float* sn = (const float*)d_in[6];
  // d_in[7] = causal mask, implemented analytically

  u16* ws    = (u16*)d_ws;
  u16* xb    = ws;                         // [2048][2048] bf16 (later aout)
  u16* wqkvT = ws + 4194304;               // [3072][2048] bf16 (later Kf/Vf)
  u16* qkv   = ws + 10485760;              // [2048][3072] bf16; QKV partial z=0 in place
  u16* woT   = ws + 16777216;              // [2048][2048] bf16
  u16* ext   = ws + 20971520;              // [2048][3072] bf16: QKV partial z=1
  u16* Kf    = wqkvT;                      // [8][64][4][2][32][8] after QKV gemm
  u16* Vf    = wqkvT + 1048576;
  u16* aout  = xb;
  u16* op0   = qkv;                        // out-proj partials (qkv region free)
  u16* op1   = ext;

  xconv<<<4096, 256, 0, stream>>>(x, xb);
  wtrans<<<dim3(64, 64), 256, 0, stream>>>(wq, wqkvT, 2048, 2048);
  wtrans<<<dim3(16, 64), 256, 0, stream>>>(wk, wqkvT + (size_t)2048 * 2048, 512, 2048);
  wtrans<<<dim3(16, 64), 256, 0, stream>>>(wv, wqkvT + (size_t)2560 * 2048, 512, 2048);
  wtrans<<<dim3(64, 64), 256, 0, stream>>>(wo, woT, 2048, 2048);

  // QKV: [2048][3072], split-K x2 (768 blocks), BK=64
  gemm_sk<<<dim3(24, 16, 2), 256, 0, stream>>>(xb, wqkvT, qkv, ext, 3072, 2048, 1024);
  reduce_qkv<<<3072, 256, 0, stream>>>(qkv, ext, Kf, Vf, cs, sn);
  attn_fwd<<<dim3(32, 32), 256, 0, stream>>>(qkv, Kf, Vf, aout);
  // out-proj: [2048][2048], split-K x2 (512 blocks), BK=64
  gemm_sk<<<dim3(16, 16, 2), 256, 0, stream>>>(aout, woT, op0, op1, 2048, 2048, 1024);
  reduce_out<<<2048, 256, 0, stream>>>(op0, op1, (float*)d_out);
}

// Round 15
// 130.432 us; speedup vs baseline: 1.2704x; 1.0580x over previous
//
#include <hip/hip_runtime.h>

typedef unsigned short u16;
typedef unsigned u32;
typedef u16 u16x8 __attribute__((ext_vector_type(8)));
typedef u16 u16x4 __attribute__((ext_vector_type(4)));
typedef u32 u32x4 __attribute__((ext_vector_type(4)));
typedef __bf16 bf8 __attribute__((ext_vector_type(8)));
typedef float f32x4 __attribute__((ext_vector_type(4)));
typedef float f32x16 __attribute__((ext_vector_type(16)));

__device__ __forceinline__ u16 f2b(float f) {
  unsigned u = __float_as_uint(f);
  u += 0x7FFFu + ((u >> 16) & 1u);   // RNE
  return (u16)(u >> 16);
}
__device__ __forceinline__ float b2f(u16 h) {
  return __uint_as_float(((unsigned)h) << 16);
}
__device__ __forceinline__ bf8 asbf8(u16x8 v) {
  return __builtin_bit_cast(bf8, v);
}
__device__ __forceinline__ void gll16(const u16* g, u16* l) {
  __builtin_amdgcn_global_load_lds(
      (const __attribute__((address_space(1))) unsigned*)(g),
      (__attribute__((address_space(3))) unsigned*)(l), 16, 0, 0);
}
__device__ __forceinline__ u32 cvtpk(float lo, float hi) {
  u32 r;
  asm("v_cvt_pk_bf16_f32 %0, %1, %2" : "=v"(r) : "v"(lo), "v"(hi));
  return r;
}
// v_permlane32_swap_b32 a, b:  a.hi32lanes <-> b.lo32lanes
__device__ __forceinline__ void plswap(u32& a, u32& b) {
  asm("v_permlane32_swap_b32 %0, %1" : "+v"(a), "+v"(b));
}
__device__ __forceinline__ float ex2(float x) {
  return __builtin_amdgcn_exp2f(x);
}
#define MFMA32(A,B,C) __builtin_amdgcn_mfma_f32_32x32x16_bf16(A,B,C,0,0,0)

// ---------------- fused prep: xconv + 4x wtrans in one dispatch ----------

__global__ __launch_bounds__(256) void prep_all(const float* __restrict__ x,
                                                const float* __restrict__ wqp,
                                                const float* __restrict__ wkp,
                                                const float* __restrict__ wvp,
                                                const float* __restrict__ wop,
                                                u16* __restrict__ xb,
                                                u16* __restrict__ wqkvT,
                                                u16* __restrict__ woT) {
  const int bid = blockIdx.x;
  if (bid < 4096) {                    // xconv
    int i = (bid * 256 + threadIdx.x) * 4;
    float4 v = *(const float4*)(x + i);
    u16x4 o;
    o[0] = f2b(v.x); o[1] = f2b(v.y); o[2] = f2b(v.z); o[3] = f2b(v.w);
    *(u16x4*)(xb + i) = o;
    return;
  }
  __shared__ float tile[32][33];
  const float* in; u16* out; int N, bx, by;
  if (bid < 8192)       { int b = bid - 4096;  in = wqp; out = wqkvT;                         N = 2048; bx = b & 63; by = b >> 6; }
  else if (bid < 9216)  { int b = bid - 8192;  in = wkp; out = wqkvT + (size_t)2048 * 2048;   N = 512;  bx = b & 15; by = b >> 4; }
  else if (bid < 10240) { int b = bid - 9216;  in = wvp; out = wqkvT + (size_t)2560 * 2048;   N = 512;  bx = b & 15; by = b >> 4; }
  else                  { int b = bid - 10240; in = wop; out = woT;                           N = 2048; bx = b & 63; by = b >> 6; }
  const int K = 2048;
  int tx = threadIdx.x & 31, ty = threadIdx.x >> 5;
  int n0 = bx * 32, k0 = by * 32;
#pragma unroll
  for (int yy = 0; yy < 32; yy += 8)
    tile[ty + yy][tx] = in[(size_t)(k0 + ty + yy) * N + n0 + tx];
  __syncthreads();
#pragma unroll
  for (int yy = 0; yy < 32; yy += 8)
    out[(size_t)(n0 + ty + yy) * K + k0 + tx] = f2b(tile[tx][ty + yy]);
}

// split-K reduce + RoPE + fused KV fragment repack.
__global__ __launch_bounds__(256) void reduce_qkv(u16* __restrict__ p0,
                                                  const u16* __restrict__ p1,
                                                  u16* __restrict__ Kf,
                                                  u16* __restrict__ Vf,
                                                  const float* __restrict__ cs,
                                                  const float* __restrict__ sn) {
  int idx = blockIdx.x * 256 + threadIdx.x;      // 2048*384
  int s = idx / 384, c8 = (idx % 384) * 8;
  size_t base = (size_t)s * 3072 + c8;
  if (c8 < 2560) {                               // q or k head: RoPE pairs
    int hc = c8 & 63;
    if (hc >= 32) return;                        // partner handles
    u16x8 a0 = *(const u16x8*)(p0 + base);
    u16x8 a1 = *(const u16x8*)(p1 + base);
    u16x8 b0 = *(const u16x8*)(p0 + base + 32);
    u16x8 b1 = *(const u16x8*)(p1 + base + 32);
    u16x8 oa, ob;
#pragma unroll
    for (int e = 0; e < 8; ++e) {
      float va = b2f(a0[e]) + b2f(a1[e]);
      float vb = b2f(b0[e]) + b2f(b1[e]);
      float c1 = cs[s * 64 + hc + e],      s1 = sn[s * 64 + hc + e];
      float c2 = cs[s * 64 + hc + 32 + e], s2 = sn[s * 64 + hc + 32 + e];
      oa[e] = f2b(va * c1 - vb * s1);
      ob[e] = f2b(vb * c2 + va * s2);
    }
    if (c8 < 2048) {                             // Q: back to qkv
      *(u16x8*)(p0 + base)      = oa;
      *(u16x8*)(p0 + base + 32) = ob;
    } else {                                     // K: to fragment-major Kf
      int kh = (c8 - 2048) >> 6;
      int d0 = hc;                               // < 32, multiple of 8
      int b = s >> 5, la = s & 31;
      int j0 = d0 >> 4, hi0 = (d0 >> 3) & 1;
      size_t f0 = ((((size_t)(kh * 64 + b) * 4 + j0) * 2 + hi0) * 32 + la) * 8;
      size_t f1 = ((((size_t)(kh * 64 + b) * 4 + j0 + 2) * 2 + hi0) * 32 + la) * 8;
      *(u16x8*)(Kf + f0) = oa;
      *(u16x8*)(Kf + f1) = ob;
    }
  } else {                                       // V: sum -> Vf fragments
    u16x8 a0 = *(const u16x8*)(p0 + base);
    u16x8 a1 = *(const u16x8*)(p1 + base);
    int c = c8 - 2560;
    int kh = c >> 6, d0 = c & 63;
    int m = d0 >> 5, la0 = d0 & 31;
    int b = s >> 5, s5 = s & 31;
    int jj = s5 >> 4, hi = (s5 >> 3) & 1, e = s5 & 7;
    u16* dst = Vf + (((size_t)(kh * 64 + b) * 4 + m * 2 + jj) * 64 + hi * 32 + la0) * 8 + e;
#pragma unroll
    for (int i = 0; i < 8; ++i)
      dst[i * 8] = f2b(b2f(a0[i]) + b2f(a1[i]));
  }
}

// split-K reduce for out-proj -> f32 d_out
__global__ __launch_bounds__(256) void reduce_out(const u16* __restrict__ p0,
                                                  const u16* __restrict__ p1,
                                                  float* __restrict__ out) {
  int idx = blockIdx.x * 256 + threadIdx.x;      // 2048*256
  size_t base = (size_t)idx * 8;
  u16x8 a0 = *(const u16x8*)(p0 + base);
  u16x8 a1 = *(const u16x8*)(p1 + base);
  float4 lo, hi;
  lo.x = b2f(a0[0]) + b2f(a1[0]); lo.y = b2f(a0[1]) + b2f(a1[1]);
  lo.z = b2f(a0[2]) + b2f(a1[2]); lo.w = b2f(a0[3]) + b2f(a1[3]);
  hi.x = b2f(a0[4]) + b2f(a1[4]); hi.y = b2f(a0[5]) + b2f(a1[5]);
  hi.z = b2f(a0[6]) + b2f(a1[6]); hi.w = b2f(a0[7]) + b2f(a1[7]);
  *(float4*)(out + base)     = lo;
  *(float4*)(out + base + 4) = hi;
}

// ------- split-K GEMM, BK=64, XOR-swizzled LDS ----------------------------

__global__ __launch_bounds__(256) void gemm_sk(const u16* __restrict__ A,
                                               const u16* __restrict__ Bt,
                                               u16* __restrict__ C0,
                                               u16* __restrict__ C1,
                                               int N, int Kfull, int KH) {
  __shared__ __align__(16) u16 As[128 * 64];
  __shared__ __align__(16) u16 Bs[128 * 64];
  const int t = threadIdx.x;
  const int lane = t & 63, wid = t >> 6;
  const int wm = (wid >> 1) * 64, wn = (wid & 1) * 64;
  const int la = lane & 15, lg = lane >> 4;
  const int m0 = blockIdx.y * 128, n0 = blockIdx.x * 128;
  const int kbeg = blockIdx.z * KH;
  u16* C = blockIdx.z ? C1 : C0;

  const int srow0 = wid * 32 + (lane >> 3);
  const int scolsw = (((lane & 7) ^ (lane >> 3))) * 8;   // pre-swizzled col
  const u16* Ap = A + (size_t)(m0 + srow0) * Kfull + kbeg + scolsw;
  const u16* Bp = Bt + (size_t)(n0 + srow0) * Kfull + kbeg + scolsw;
  u16* Adst = &As[wid * 2048];
  u16* Bdst = &Bs[wid * 2048];
  const size_t rstep8 = (size_t)8 * Kfull;

  f32x4 acc[4][4] = {};

  for (int k0 = 0; k0 < KH; k0 += 64) {
    __syncthreads();
#pragma unroll
    for (int cc = 0; cc < 4; ++cc)
      gll16(Ap + k0 + cc * rstep8, Adst + cc * 512);
#pragma unroll
    for (int cc = 0; cc < 4; ++cc)
      gll16(Bp + k0 + cc * rstep8, Bdst + cc * 512);
    __syncthreads();
#pragma unroll
    for (int kk = 0; kk < 2; ++kk) {
      bf8 af[4], bfr[4];
#pragma unroll
      for (int i = 0; i < 4; ++i) {
        const int row = wm + i * 16 + la;
        const int c8 = (kk * 4 + lg) ^ (row & 7);
        af[i] = asbf8(*(const u16x8*)(&As[row * 64 + c8 * 8]));
      }
#pragma unroll
      for (int j = 0; j < 4; ++j) {
        const int row = wn + j * 16 + la;
        const int c8 = (kk * 4 + lg) ^ (row & 7);
        bfr[j] = asbf8(*(const u16x8*)(&Bs[row * 64 + c8 * 8]));
      }
      __builtin_amdgcn_s_setprio(1);
#pragma unroll
      for (int i = 0; i < 4; ++i)
#pragma unroll
        for (int j = 0; j < 4; ++j)
          acc[i][j] = __builtin_amdgcn_mfma_f32_16x16x32_bf16(af[i], bfr[j],
                                                              acc[i][j], 0, 0, 0);
      __builtin_amdgcn_s_setprio(0);
    }
  }

#pragma unroll
  for (int i = 0; i < 4; ++i)
#pragma unroll
    for (int j = 0; j < 4; ++j)
#pragma unroll
      for (int r = 0; r < 4; ++r) {
        int row = m0 + wm + i * 16 + lg * 4 + r;
        int col = n0 + wn + j * 16 + la;
        C[(size_t)row * N + col] = f2b(acc[i][j][r]);
      }
}

// --- flash attention: LDS-shared KV, counted-vmcnt pipeline (T4) ----------
// Block = (head, 64 q rows), 4 waves = 2 q-tiles x 2 kv-halves, 32-kv steps.
// Per iter: STG(next) [4 gll16/wave] -> s_waitcnt vmcnt(4) (cur's loads are
// the older 4 -> done; next's stay IN FLIGHT across the barrier) -> raw
// s_barrier -> compute -> raw s_barrier. No vmcnt(0) drain in steady state.
// Static-max softmax (shared m=32); 2-half merge = plain LDS sum.

#define STEPL(buf, bb) do {                                          \
    const u16* p_ = &smem[(((h2) << 1) | (buf)) * 4096 + lane8];     \
    bf8 K0 = asbf8(*(const u16x8*)(p_));                             \
    bf8 K1 = asbf8(*(const u16x8*)(p_ + 512));                       \
    bf8 K2 = asbf8(*(const u16x8*)(p_ + 1024));                      \
    bf8 K3 = asbf8(*(const u16x8*)(p_ + 1536));                      \
    bf8 V0 = asbf8(*(const u16x8*)(p_ + 2048));                      \
    bf8 V1 = asbf8(*(const u16x8*)(p_ + 2560));                      \
    bf8 V2 = asbf8(*(const u16x8*)(p_ + 3072));                      \
    bf8 V3 = asbf8(*(const u16x8*)(p_ + 3584));                      \
    f32x16 s = {};                                                   \
    __builtin_amdgcn_s_setprio(1);                                   \
    s = MFMA32(K0, qf0, s);                                          \
    s = MFMA32(K1, qf1, s);                                          \
    s = MFMA32(K2, qf2, s);                                          \
    s = MFMA32(K3, qf3, s);                                          \
    __builtin_amdgcn_s_setprio(0);                                   \
    if ((bb) == kmax) {                                              \
      _Pragma("unroll") for (int r = 0; r < 16; ++r) {               \
        int kvr = (bb) * 32 + (r & 3) + 8 * (r >> 2) + 4 * hi;       \
        if (kvr > q0w + la) s[r] = -1e30f;                           \
      }                                                              \
    }                                                                \
    _Pragma("unroll") for (int r = 0; r < 16; ++r)                   \
      s[r] = ex2(s[r] - 32.0f);                                      \
    float z0 = s[0] + s[1],   z1 = s[2] + s[3];                      \
    float z2 = s[4] + s[5],   z3 = s[6] + s[7];                      \
    float z4 = s[8] + s[9],   z5 = s[10] + s[11];                    \
    float z6 = s[12] + s[13], z7 = s[14] + s[15];                    \
    l_run += ((z0 + z1) + (z2 + z3)) + ((z4 + z5) + (z6 + z7));      \
    u32 c0 = cvtpk(s[0], s[1]),   c1 = cvtpk(s[2], s[3]);            \
    u32 c2 = cvtpk(s[4], s[5]),   c3 = cvtpk(s[6], s[7]);            \
    u32 c4 = cvtpk(s[8], s[9]),   c5 = cvtpk(s[10], s[11]);          \
    u32 c6 = cvtpk(s[12], s[13]), c7 = cvtpk(s[14], s[15]);          \
    plswap(c0, c2); plswap(c1, c3); plswap(c4, c6); plswap(c5, c7);  \
    u32x4 t0; t0[0] = c0; t0[1] = c1; t0[2] = c2; t0[3] = c3;        \
    u32x4 t1; t1[0] = c4; t1[1] = c5; t1[2] = c6; t1[3] = c7;        \
    bf8 pa0 = __builtin_bit_cast(bf8, t0);                           \
    bf8 pa1 = __builtin_bit_cast(bf8, t1);                           \
    __builtin_amdgcn_s_setprio(1);                                   \
    o0 = MFMA32(pa0, V0, o0);                                        \
    o0 = MFMA32(pa1, V1, o0);                                        \
    o1 = MFMA32(pa0, V2, o1);                                        \
    o1 = MFMA32(pa1, V3, o1);                                        \
    __builtin_amdgcn_s_setprio(0);                                   \
  } while (0)

// wave w stages its own half's block: 4 x gll16 (K 2x512, V 2x512)
#define STG(bb, buf) do {                                            \
    u16* d_ = &smem[((((h2) << 1) | (buf)) * 4096) + wq * 1024];     \
    const u16* kp_ = Kg + (size_t)(bb) * 2048 + wq * 1024 + lane8;   \
    const u16* vp_ = Vg + (size_t)(bb) * 2048 + wq * 1024 + lane8;   \
    gll16(kp_, d_);                                                  \
    gll16(kp_ + 512, d_ + 512);                                      \
    gll16(vp_, d_ + 2048);                                           \
    gll16(vp_ + 512, d_ + 2560);                                     \
  } while (0)

__global__ __launch_bounds__(256, 4) void attn_fwd(const u16* __restrict__ qkv,
                                                   const u16* __restrict__ Kf,
                                                   const u16* __restrict__ Vf,
                                                   u16* __restrict__ aout) {
  const int head = blockIdx.x;
  const int qt = 31 - (int)blockIdx.y;   // heavy q-blocks dispatch first
  const int Q0 = qt * 64;
  const int Kb = qt * 2;                 // kv-block index of Q0
  const int nb = Kb + 2;                 // kv blocks total (even)
  const int ha = nb >> 1;                // steps; half A: [0,ha), B: [ha,nb)
  const int kh = head >> 2;              // GROUPS = 4
  const int t = threadIdx.x;
  const int w = t >> 6, lane = t & 63;
  const int h2 = w >> 1;                 // kv half
  const int wq = w & 1;                  // q sub-tile / staging sub
  const int la = lane & 31;
  const int hi = lane >> 5;
  const int lane8 = lane * 8;
  const int q0w = Q0 + 32 * wq;
  const int kmax = Kb + wq;              // this wave's diagonal kv-block

  // staging: 4 slots (half,buf) x 4096 u16 (K 2048 | V 2048) = 32 KB
  // merge overlay: [4][32][72] u16 = 9216 u16, reused post-loop
  __shared__ __align__(16) u16 smem[16384];
  __shared__ float lM[4][32];

  // Q B-fragments, prescaled by 0.125*log2(e) (base-2 softmax domain)
  bf8 qf0, qf1, qf2, qf3;
  {
    const u16* qp = qkv + (size_t)(q0w + la) * 3072 + head * 64 + hi * 8;
    const float SC = 0.125f * 1.44269504088896340736f;
#define QLOAD(dst, kk) do {                                          \
      u16x8 v = *(const u16x8*)(qp + (kk) * 16);                     \
      u16x8 sv;                                                      \
      _Pragma("unroll") for (int e = 0; e < 8; ++e)                  \
        sv[e] = f2b(b2f(v[e]) * SC);                                 \
      dst = asbf8(sv);                                               \
    } while (0)
    QLOAD(qf0, 0); QLOAD(qf1, 1); QLOAD(qf2, 2); QLOAD(qf3, 3);
#undef QLOAD
  }

  const u16* Kg = Kf + (size_t)kh * 131072;
  const u16* Vg = Vf + (size_t)kh * 131072;

  f32x16 o0 = {}, o1 = {};
  float l_run = 0.f;

  STG(h2 ? ha : 0, 0);                   // prologue: first tile into buf 0

  for (int i = 0; i < ha; ++i) {
    const bool pf = (i + 1 < ha);        // uniform across all waves
    if (pf) STG(h2 ? (ha + i + 1) : (i + 1), (i + 1) & 1);
    if (pf) asm volatile("s_waitcnt vmcnt(4)" ::: "memory");
    else    asm volatile("s_waitcnt vmcnt(0)" ::: "memory");
    __builtin_amdgcn_s_barrier();        // all waves' cur-tile loads landed
    __builtin_amdgcn_sched_barrier(0);
    const int bb = h2 ? (ha + i) : i;
    if (bb <= kmax) STEPL(i & 1, bb);
    __builtin_amdgcn_sched_barrier(0);
    __builtin_amdgcn_s_barrier();        // reads done before next overwrite
  }

  // publish partials: l (half-combined) and O (bf16) into overlay
  {
    float lt = l_run + __shfl_xor(l_run, 32);
    if (lane < 32) lM[w][lane] = lt;
#pragma unroll
    for (int r = 0; r < 16; ++r) {
      int crow = (r & 3) + 8 * (r >> 2) + 4 * hi;
      smem[(w * 32 + crow) * 72 + la]      = f2b(o0[r]);
      smem[(w * 32 + crow) * 72 + la + 32] = f2b(o1[r]);
    }
  }
  __syncthreads();

  // merge: plain sums (shared m=32). 512 items (64 q x 8 d-chunks)
#pragma unroll
  for (int it = 0; it < 2; ++it) {
    const int id = t + it * 256;
    const int q = id >> 3, d0 = (id & 7) * 8;
    const int wA = q >> 5, crow = q & 31;
    float inv = 1.0f / (lM[wA][crow] + lM[wA + 2][crow]);
    u16x8 a = *(const u16x8*)&smem[((wA)     * 32 + crow) * 72 + d0];
    u16x8 b = *(const u16x8*)&smem[((wA + 2) * 32 + crow) * 72 + d0];
    u16x8 outv;
#pragma unroll
    for (int j = 0; j < 8; ++j)
      outv[j] = f2b((b2f(a[j]) + b2f(b[j])) * inv);
    *(u16x8*)(aout + (size_t)(Q0 + q) * 2048 + head * 64 + d0) = outv;
  }
}

// ---------------- launch ----------------

extern "C" void kernel_launch(void* const* d_in, const int* in_sizes, int n_in,
                              void* d_out, int out_size, void* d_ws, size_t ws_size,
                              hipStream_t stream) {
  (void)in_sizes; (void)n_in; (void)out_size; (void)ws_size;
  const float* x  = (const float*)d_in[0];
  const float* wq = (const float*)d_in[1];
  const float* wk = (const float*)d_in[2];
  const float* wv = (const float*)d_in[3];
  const float* wo = (const float*)d_in[4];
  const float* cs = (const float*)d_in[5];
  const float* sn = (const float*)d_in[6];
  // d_in[7] = causal mask, implemented analytically

  u16* ws    = (u16*)d_ws;
  u16* xb    = ws;                         // [2048][2048] bf16 (later aout)
  u16* wqkvT = ws + 4194304;               // [3072][2048] bf16 (later Kf/Vf)
  u16* qkv   = ws + 10485760;              // [2048][3072] bf16; QKV partial z=0 in place
  u16* woT   = ws + 16777216;              // [2048][2048] bf16
  u16* ext   = ws + 20971520;              // [2048][3072] bf16: QKV partial z=1
  u16* Kf    = wqkvT;                      // [8][64][4][2][32][8] after QKV gemm
  u16* Vf    = wqkvT + 1048576;
  u16* aout  = xb;
  u16* op0   = qkv;                        // out-proj partials (qkv region free)
  u16* op1   = ext;

  prep_all<<<14336, 256, 0, stream>>>(x, wq, wk, wv, wo, xb, wqkvT, woT);

  // QKV: [2048][3072], split-K x2 (768 blocks), BK=64
  gemm_sk<<<dim3(24, 16, 2), 256, 0, stream>>>(xb, wqkvT, qkv, ext, 3072, 2048, 1024);
  reduce_qkv<<<3072, 256, 0, stream>>>(qkv, ext, Kf, Vf, cs, sn);
  attn_fwd<<<dim3(32, 32), 256, 0, stream>>>(qkv, Kf, Vf, aout);
  // out-proj: [2048][2048], split-K x2 (512 blocks), BK=64
  gemm_sk<<<dim3(16, 16, 2), 256, 0, stream>>>(aout, woT, op0, op1, 2048, 2048, 1024);
  reduce_out<<<2048, 256, 0, stream>>>(op0, op1, (float*)d_out);
}